// Round 9
// baseline (9115.697 us; speedup 1.0000x reference)
//
#include <hip/hip_runtime.h>

#define LOG2E 1.4426950408889634f

// ---------------- ws layout (bytes) ----------------
#define WK_OFF   ((size_t)0)          // wk_eff f32 [8][512]
#define KB_OFF   ((size_t)16384)      // kbias f32 [8]
#define Q2_OFF   ((size_t)16416)      // q2 f32 [512]
#define SEG_OFF  ((size_t)18464)      // seg i32 [4097]
#define S_OFF    ((size_t)34880)      // S_ws bf16 [8][4096][512]
#define ATTN_OFF ((size_t)33589312)   // attn bf16 [4096][512]
#define WVHI_OFF ((size_t)37783616)   // Wv hi bf16 [512*512]
#define WVLO_OFF ((size_t)38307904)
#define WOHI_OFF ((size_t)38832192)
#define WOLO_OFF ((size_t)39356480)
#define WS_NEEDED ((size_t)39880768)
// probe: duplicate k_main output region (32 MB)
#define SDUP_OFF ((size_t)39880768)
#define WS_PROBE (SDUP_OFF + (size_t)8*4096*512*2)

typedef __bf16 bf16x8 __attribute__((ext_vector_type(8)));
typedef float f32x4 __attribute__((ext_vector_type(4)));

__device__ __forceinline__ float readlane_f(float v, int l) {
  return __int_as_float(__builtin_amdgcn_readlane(__float_as_int(v), l));
}

__device__ __forceinline__ unsigned short f2bf(float x) {
  unsigned u = __float_as_uint(x);
  unsigned r = (u + 0x7fffu + ((u >> 16) & 1u)) >> 16;
  return (unsigned short)r;
}

__device__ __forceinline__ unsigned pack2(float x, float y) {
  return (unsigned)f2bf(x) | ((unsigned)f2bf(y) << 16);
}

__device__ __forceinline__ float bf2f(unsigned short h) {
  return __uint_as_float((unsigned)h << 16);
}

// ---------------- K0: fused prep (W hi/lo split + seg lower_bound + q2) ----------------
__global__ __launch_bounds__(256) void k_prep(
    const float* __restrict__ Wv, const float* __restrict__ Wo,
    unsigned short* __restrict__ wvhi, unsigned short* __restrict__ wvlo,
    unsigned short* __restrict__ wohi, unsigned short* __restrict__ wolo,
    const void* __restrict__ batch, int n, int* __restrict__ seg,
    const float* __restrict__ qry, const float* __restrict__ Wq,
    const float* __restrict__ bq, float* __restrict__ q2) {
  int bx = blockIdx.x;
  if (bx < 1024) {
    int i = bx * 256 + threadIdx.x;
    float v = Wv[i];
    unsigned short h = f2bf(v);
    wvhi[i] = h;
    wvlo[i] = f2bf(v - bf2f(h));
    float o = Wo[i];
    unsigned short h2 = f2bf(o);
    wohi[i] = h2;
    wolo[i] = f2bf(o - bf2f(h2));
  } else if (bx < 1041) {
    int b = (bx - 1024) * 256 + threadIdx.x;
    if (b > 4096) return;
    const int* b32 = (const int*)batch;
    const long long* b64 = (const long long*)batch;
    bool is64 = (b32[n - 1] == 0);
    int lo = 0, hi = n;
    while (lo < hi) {
      int mid = (lo + hi) >> 1;
      long long v = is64 ? b64[mid] : (long long)b32[mid];
      if (v < (long long)b) lo = mid + 1; else hi = mid;
    }
    seg[b] = lo;
  } else {
    int d = (bx - 1041) * 256 + threadIdx.x;
    const float4* q4 = (const float4*)qry;
    const float4* w4 = (const float4*)(Wq + (size_t)d * 512);
    float acc = 0.f;
    #pragma unroll 4
    for (int j = 0; j < 128; ++j) {
      float4 a = q4[j], b = w4[j];
      acc += a.x * b.x + a.y * b.y + a.z * b.z + a.w * b.w;
    }
    q2[d] = (acc + bq[d]) * (0.125f * LOG2E);
  }
}

// ---------------- K1: wk_eff + kbias ----------------
__global__ __launch_bounds__(256) void k_wk(const float* __restrict__ Wk,
                                            const float* __restrict__ bk,
                                            const float* __restrict__ q2,
                                            float* __restrict__ wk,
                                            float* __restrict__ kb) {
  if (blockIdx.x == 16) {
    int h = threadIdx.x;
    if (h < 8) {
      float acc = 0.f;
      for (int dd = 0; dd < 64; ++dd) acc += q2[h * 64 + dd] * bk[h * 64 + dd];
      kb[h] = acc;
    }
    return;
  }
  int id = blockIdx.x * 256 + threadIdx.x;
  int h = id >> 9, e = id & 511;
  float acc = 0.f;
  #pragma unroll 4
  for (int dd = 0; dd < 64; ++dd)
    acc += q2[h * 64 + dd] * Wk[(size_t)(h * 64 + dd) * 512 + e];
  wk[id] = acc;
}

// ---------------- K2: dim-split fused scores+softmax+pooling ----------------
// Block = 4 waves, graph b. Iteration t processes nodes {s+2t, s+2t+1}.
// wave = (noff = node parity, half = dim half): owns 256 dims of one node.
//   -> wk regs 32, S-acc regs 32, no redundant loads, ~100 VGPR (no spill).
// Score: in-wave value-paired butterfly on the 256-dim half, then one LDS
// cell per (node,half) + RAW s_barrier (lgkmcnt(0) only -- vmcnt NOT drained,
// so the 3-deep prefetch pipeline survives across barriers).

#define PREF(T, X)                                         \
  {                                                        \
    int i_ = s + 2 * (T) + noff;                           \
    i_ = i_ < em1 ? i_ : em1;                              \
    X = emb4[(size_t)i_ * 128 + voff];                     \
  }

#define PROC(T, X)                                                              \
  {                                                                             \
    float p[8];                                                                 \
    _Pragma("unroll")                                                           \
    for (int h = 0; h < 8; ++h)                                                 \
      p[h] = X.x * wk4[h].x + X.y * wk4[h].y + X.z * wk4[h].z + X.w * wk4[h].w; \
    float q[4];                                                                 \
    _Pragma("unroll")                                                           \
    for (int i2 = 0; i2 < 4; ++i2) {                                            \
      float keep = (lane & 1) ? p[2 * i2 + 1] : p[2 * i2];                      \
      float send = (lane & 1) ? p[2 * i2] : p[2 * i2 + 1];                      \
      q[i2] = keep + __shfl_xor(send, 1);                                       \
    }                                                                           \
    float r[2];                                                                 \
    _Pragma("unroll")                                                           \
    for (int i2 = 0; i2 < 2; ++i2) {                                            \
      float keep = (lane & 2) ? q[2 * i2 + 1] : q[2 * i2];                      \
      float send = (lane & 2) ? q[2 * i2] : q[2 * i2 + 1];                      \
      r[i2] = keep + __shfl_xor(send, 2);                                       \
    }                                                                           \
    float s1;                                                                   \
    {                                                                           \
      float keep = (lane & 4) ? r[1] : r[0];                                    \
      float send = (lane & 4) ? r[0] : r[1];                                    \
      s1 = keep + __shfl_xor(send, 4);                                          \
    }                                                                           \
    s1 += __shfl_xor(s1, 8);                                                    \
    s1 += __shfl_xor(s1, 16);                                                   \
    s1 += __shfl_xor(s1, 32);                                                   \
    if (lane < 8) sc[(T) & 1][noff][half][lane] = s1;                           \
    asm volatile("s_waitcnt lgkmcnt(0)" ::: "memory");                          \
    __builtin_amdgcn_s_barrier();                                               \
    asm volatile("" ::: "memory");                                              \
    float sco = sc[(T) & 1][noff][0][lane & 7] + sc[(T) & 1][noff][1][lane & 7];\
    int nidx = s + 2 * (T) + noff;                                              \
    float wgt = (nidx < e2) ? exp2f(sco + kbl) : 0.f;                           \
    dn += wgt;                                                                  \
    float w0 = readlane_f(wgt, 0), w1 = readlane_f(wgt, 1);                     \
    float w2 = readlane_f(wgt, 2), w3 = readlane_f(wgt, 3);                     \
    float w4 = readlane_f(wgt, 4), w5 = readlane_f(wgt, 5);                     \
    float w6 = readlane_f(wgt, 6), w7 = readlane_f(wgt, 7);                     \
    S4[0].x += w0 * X.x; S4[0].y += w0 * X.y; S4[0].z += w0 * X.z; S4[0].w += w0 * X.w; \
    S4[1].x += w1 * X.x; S4[1].y += w1 * X.y; S4[1].z += w1 * X.z; S4[1].w += w1 * X.w; \
    S4[2].x += w2 * X.x; S4[2].y += w2 * X.y; S4[2].z += w2 * X.z; S4[2].w += w2 * X.w; \
    S4[3].x += w3 * X.x; S4[3].y += w3 * X.y; S4[3].z += w3 * X.z; S4[3].w += w3 * X.w; \
    S4[4].x += w4 * X.x; S4[4].y += w4 * X.y; S4[4].z += w4 * X.z; S4[4].w += w4 * X.w; \
    S4[5].x += w5 * X.x; S4[5].y += w5 * X.y; S4[5].z += w5 * X.z; S4[5].w += w5 * X.w; \
    S4[6].x += w6 * X.x; S4[6].y += w6 * X.y; S4[6].z += w6 * X.z; S4[6].w += w6 * X.w; \
    S4[7].x += w7 * X.x; S4[7].y += w7 * X.y; S4[7].z += w7 * X.z; S4[7].w += w7 * X.w; \
  }

__global__ __launch_bounds__(256, 4) void k_main(const float* __restrict__ emb,
                                                 const int* __restrict__ seg,
                                                 const float* __restrict__ wk,
                                                 const float* __restrict__ kb,
                                                 unsigned short* __restrict__ S_out,
                                                 int reps) {
  __shared__ float ep[4][2048];      // 32 KB epilogue combine
  __shared__ float sc[2][2][2][8];   // [parity][noff][half][head]
  __shared__ float dnl[2][8];        // [noff][head]

  const int tid = threadIdx.x;
  const int lane = tid & 63, wave = tid >> 6;
  const int noff = wave >> 1, half = wave & 1;
  const int b = blockIdx.x;
  const int s = seg[b], e2 = seg[b + 1];
  const int nt = e2 - s, em1 = e2 - 1;
  const int it = (nt + 1) >> 1;

  float4 wk4[8];
  #pragma unroll
  for (int h = 0; h < 8; ++h)
    wk4[h] = *(const float4*)(wk + h * 512 + half * 256 + 4 * lane);
  const float kbl = kb[lane & 7];
  const float4* emb4 = (const float4*)emb;
  const int voff = half * 64 + lane;

  for (int rep = 0; rep < reps; ++rep) {
    float4 S4[8];
    #pragma unroll
    for (int h = 0; h < 8; ++h) S4[h] = make_float4(0.f, 0.f, 0.f, 0.f);
    float dn = 0.f;

    if (it > 0) {
      float4 A, Bv, C, D;
      PREF(0, A);
      PREF(1, Bv);
      PREF(2, C);
      int t = 0;
      while (true) {
        if (t >= it) break;
        PREF(t + 3, D); PROC(t, A); ++t;
        if (t >= it) break;
        PREF(t + 3, A); PROC(t, Bv); ++t;
        if (t >= it) break;
        PREF(t + 3, Bv); PROC(t, C); ++t;
        if (t >= it) break;
        PREF(t + 3, C); PROC(t, D); ++t;
      }
    }

    // ---- epilogue: cross-wave combine (full drain OK here) ----
    __syncthreads();
    #pragma unroll
    for (int h = 0; h < 8; ++h)
      *(float4*)&ep[wave][h * 256 + 4 * lane] = S4[h];
    if ((wave & 1) == 0 && lane < 8) dnl[noff][lane] = dn;
    __syncthreads();

    const int h = tid >> 5, chunk = tid & 31;
    const int hf = chunk >> 4, inner = (chunk & 15) * 16;
    float d = dnl[0][h] + dnl[1][h];
    float invd = d > 0.f ? 1.f / d : 0.f;
    const float* pa = &ep[hf][h * 256 + inner];       // noff=0 wave for this half
    const float* pb = &ep[2 + hf][h * 256 + inner];   // noff=1 wave for this half
    unsigned short* po = S_out + ((size_t)h * 4096 + b) * 512 + hf * 256 + inner;
    float v[16];
    #pragma unroll
    for (int j = 0; j < 16; ++j) v[j] = (pa[j] + pb[j]) * invd;
    uint4 o0, o1;
    o0.x = pack2(v[0], v[1]);   o0.y = pack2(v[2], v[3]);
    o0.z = pack2(v[4], v[5]);   o0.w = pack2(v[6], v[7]);
    o1.x = pack2(v[8], v[9]);   o1.y = pack2(v[10], v[11]);
    o1.z = pack2(v[12], v[13]); o1.w = pack2(v[14], v[15]);
    *(uint4*)po = o0;
    *(uint4*)(po + 8) = o1;
    __syncthreads();  // guard ep reuse across reps
  }
}

// ---------------- K3/K4: MFMA NT GEMM ----------------
template <bool C_BF16>
__global__ __launch_bounds__(256) void k_gemm_mfma(
    const unsigned short* __restrict__ A, size_t a_cb_stride,
    const unsigned short* __restrict__ Whi, const unsigned short* __restrict__ Wlo,
    const float* __restrict__ bias, void* __restrict__ Cv) {
  const int t = threadIdx.x;
  const int lane = t & 63, wvid = t >> 6;
  const int wr = wvid >> 1, wc = wvid & 1;
  const int row16 = lane & 15;
  const int k8 = (lane >> 4) * 8;
  const int mbase = blockIdx.x * 64 + wr * 32;
  const int nbase = blockIdx.y * 64 + wc * 32;

  const unsigned short* Ap = A + (size_t)blockIdx.y * a_cb_stride +
                             (size_t)(mbase + row16) * 512 + k8;
  const unsigned short* Wh = Whi + (size_t)(nbase + row16) * 512 + k8;
  const unsigned short* Wl = Wlo + (size_t)(nbase + row16) * 512 + k8;

  f32x4 acc[2][2] = {};

  #pragma unroll 4
  for (int kk = 0; kk < 512; kk += 32) {
    bf16x8 a0 = *(const bf16x8*)(Ap + kk);
    bf16x8 a1 = *(const bf16x8*)(Ap + 16 * 512 + kk);
    bf16x8 h0 = *(const bf16x8*)(Wh + kk);
    bf16x8 h1 = *(const bf16x8*)(Wh + 16 * 512 + kk);
    bf16x8 l0 = *(const bf16x8*)(Wl + kk);
    bf16x8 l1 = *(const bf16x8*)(Wl + 16 * 512 + kk);
    acc[0][0] = __builtin_amdgcn_mfma_f32_16x16x32_bf16(a0, h0, acc[0][0], 0, 0, 0);
    acc[0][1] = __builtin_amdgcn_mfma_f32_16x16x32_bf16(a0, h1, acc[0][1], 0, 0, 0);
    acc[1][0] = __builtin_amdgcn_mfma_f32_16x16x32_bf16(a1, h0, acc[1][0], 0, 0, 0);
    acc[1][1] = __builtin_amdgcn_mfma_f32_16x16x32_bf16(a1, h1, acc[1][1], 0, 0, 0);
    acc[0][0] = __builtin_amdgcn_mfma_f32_16x16x32_bf16(a0, l0, acc[0][0], 0, 0, 0);
    acc[0][1] = __builtin_amdgcn_mfma_f32_16x16x32_bf16(a0, l1, acc[0][1], 0, 0, 0);
    acc[1][0] = __builtin_amdgcn_mfma_f32_16x16x32_bf16(a1, l0, acc[1][0], 0, 0, 0);
    acc[1][1] = __builtin_amdgcn_mfma_f32_16x16x32_bf16(a1, l1, acc[1][1], 0, 0, 0);
  }

  const int r4 = (lane >> 4) * 4;
  #pragma unroll
  for (int c = 0; c < 2; ++c) {
    const float bc = bias[nbase + c * 16 + row16];
    #pragma unroll
    for (int r = 0; r < 2; ++r) {
      #pragma unroll
      for (int j = 0; j < 4; ++j) {
        float v = acc[r][c][j] + bc;
        size_t row = (size_t)(mbase + r * 16 + r4 + j);
        size_t col = (size_t)(nbase + c * 16 + row16);
        if (C_BF16)
          ((unsigned short*)Cv)[row * 512 + col] = f2bf(v);
        else
          ((float*)Cv)[row * 512 + col] = v;
      }
    }
  }
}

// ---------------- launcher ----------------
extern "C" void kernel_launch(void* const* d_in, const int* in_sizes, int n_in,
                              void* d_out, int out_size, void* d_ws, size_t ws_size,
                              hipStream_t stream) {
  const float* emb   = (const float*)d_in[0];
  const void*  batch = d_in[1];
  const float* qry   = (const float*)d_in[2];
  const float* Wq    = (const float*)d_in[3];
  const float* bq    = (const float*)d_in[4];
  const float* Wk    = (const float*)d_in[5];
  const float* bk    = (const float*)d_in[6];
  const float* Wv    = (const float*)d_in[7];
  const float* bv    = (const float*)d_in[8];
  const float* Wo    = (const float*)d_in[9];
  const float* bo    = (const float*)d_in[10];
  const int N = in_sizes[1];

  if (ws_size < WS_NEEDED) return;

  char* ws = (char*)d_ws;
  float* wk_eff = (float*)(ws + WK_OFF);
  float* kbias  = (float*)(ws + KB_OFF);
  float* q2     = (float*)(ws + Q2_OFF);
  int*   seg    = (int*)(ws + SEG_OFF);
  unsigned short* S_ws = (unsigned short*)(ws + S_OFF);
  unsigned short* attn = (unsigned short*)(ws + ATTN_OFF);
  unsigned short* wvhi = (unsigned short*)(ws + WVHI_OFF);
  unsigned short* wvlo = (unsigned short*)(ws + WVLO_OFF);
  unsigned short* wohi = (unsigned short*)(ws + WOHI_OFF);
  unsigned short* wolo = (unsigned short*)(ws + WOLO_OFF);

  k_prep<<<1043, 256, 0, stream>>>(Wv, Wo, wvhi, wvlo, wohi, wolo,
                                   batch, N, seg, qry, Wq, bq, q2);
  k_wk  <<<17, 256, 0, stream>>>(Wk, bk, q2, wk_eff, kbias);
  k_main<<<4096, 256, 0, stream>>>(emb, seg, wk_eff, kbias, S_ws, 1);

  // ---- PROBE: one dispatch, 4 internal reps into scratch. Surfaces in
  // rocprof top-5 with k_main's true VGPR/WRITE_SIZE (spill check) and BW.
  if (ws_size >= WS_PROBE) {
    unsigned short* S_dup = (unsigned short*)(ws + SDUP_OFF);
    k_main<<<4096, 256, 0, stream>>>(emb, seg, wk_eff, kbias, S_dup, 4);
  }

  dim3 g(64, 8);
  k_gemm_mfma<true ><<<g, 256, 0, stream>>>(S_ws, (size_t)4096 * 512, wvhi, wvlo, bv, attn);
  k_gemm_mfma<false><<<g, 256, 0, stream>>>(attn, 0, wohi, wolo, bo, d_out);
}

// Round 10
// 1199.361 us; speedup vs baseline: 7.6005x; 7.6005x over previous
//
#include <hip/hip_runtime.h>

#define LOG2E 1.4426950408889634f

// ---------------- ws layout (bytes) ----------------
#define WK_OFF   ((size_t)0)          // wk_eff f32 [8][512]
#define KB_OFF   ((size_t)16384)      // kbias f32 [8]
#define Q2_OFF   ((size_t)16416)      // q2 f32 [512]
#define SEG_OFF  ((size_t)18464)      // seg i32 [4097]
#define S_OFF    ((size_t)34880)      // S_ws bf16 [8][4096][512]
#define ATTN_OFF ((size_t)33589312)   // attn bf16 [4096][512]
#define WVHI_OFF ((size_t)37783616)   // Wv hi bf16 [512*512]
#define WVLO_OFF ((size_t)38307904)
#define WOHI_OFF ((size_t)38832192)
#define WOLO_OFF ((size_t)39356480)
#define WS_NEEDED ((size_t)39880768)
// probe: duplicate k_main output region (32 MB)
#define SDUP_OFF ((size_t)39880768)
#define WS_PROBE (SDUP_OFF + (size_t)8*4096*512*2)

typedef __bf16 bf16x8 __attribute__((ext_vector_type(8)));
typedef float f32x4 __attribute__((ext_vector_type(4)));

__device__ __forceinline__ float readlane_f(float v, int l) {
  return __int_as_float(__builtin_amdgcn_readlane(__float_as_int(v), l));
}

__device__ __forceinline__ unsigned short f2bf(float x) {
  unsigned u = __float_as_uint(x);
  unsigned r = (u + 0x7fffu + ((u >> 16) & 1u)) >> 16;
  return (unsigned short)r;
}

__device__ __forceinline__ unsigned pack2(float x, float y) {
  return (unsigned)f2bf(x) | ((unsigned)f2bf(y) << 16);
}

__device__ __forceinline__ float bf2f(unsigned short h) {
  return __uint_as_float((unsigned)h << 16);
}

// ---------------- K0: fused prep (W hi/lo split + seg lower_bound + q2) ----------------
__global__ __launch_bounds__(256) void k_prep(
    const float* __restrict__ Wv, const float* __restrict__ Wo,
    unsigned short* __restrict__ wvhi, unsigned short* __restrict__ wvlo,
    unsigned short* __restrict__ wohi, unsigned short* __restrict__ wolo,
    const void* __restrict__ batch, int n, int* __restrict__ seg,
    const float* __restrict__ qry, const float* __restrict__ Wq,
    const float* __restrict__ bq, float* __restrict__ q2) {
  int bx = blockIdx.x;
  if (bx < 1024) {
    int i = bx * 256 + threadIdx.x;
    float v = Wv[i];
    unsigned short h = f2bf(v);
    wvhi[i] = h;
    wvlo[i] = f2bf(v - bf2f(h));
    float o = Wo[i];
    unsigned short h2 = f2bf(o);
    wohi[i] = h2;
    wolo[i] = f2bf(o - bf2f(h2));
  } else if (bx < 1041) {
    int b = (bx - 1024) * 256 + threadIdx.x;
    if (b > 4096) return;
    const int* b32 = (const int*)batch;
    const long long* b64 = (const long long*)batch;
    bool is64 = (b32[n - 1] == 0);
    int lo = 0, hi = n;
    while (lo < hi) {
      int mid = (lo + hi) >> 1;
      long long v = is64 ? b64[mid] : (long long)b32[mid];
      if (v < (long long)b) lo = mid + 1; else hi = mid;
    }
    seg[b] = lo;
  } else {
    int d = (bx - 1041) * 256 + threadIdx.x;
    const float4* q4 = (const float4*)qry;
    const float4* w4 = (const float4*)(Wq + (size_t)d * 512);
    float acc = 0.f;
    #pragma unroll 4
    for (int j = 0; j < 128; ++j) {
      float4 a = q4[j], b = w4[j];
      acc += a.x * b.x + a.y * b.y + a.z * b.z + a.w * b.w;
    }
    q2[d] = (acc + bq[d]) * (0.125f * LOG2E);
  }
}

// ---------------- K1: wk_eff + kbias ----------------
__global__ __launch_bounds__(256) void k_wk(const float* __restrict__ Wk,
                                            const float* __restrict__ bk,
                                            const float* __restrict__ q2,
                                            float* __restrict__ wk,
                                            float* __restrict__ kb) {
  if (blockIdx.x == 16) {
    int h = threadIdx.x;
    if (h < 8) {
      float acc = 0.f;
      for (int dd = 0; dd < 64; ++dd) acc += q2[h * 64 + dd] * bk[h * 64 + dd];
      kb[h] = acc;
    }
    return;
  }
  int id = blockIdx.x * 256 + threadIdx.x;
  int h = id >> 9, e = id & 511;
  float acc = 0.f;
  #pragma unroll 4
  for (int dd = 0; dd < 64; ++dd)
    acc += q2[h * 64 + dd] * Wk[(size_t)(h * 64 + dd) * 512 + e];
  wk[id] = acc;
}

// ---------------- K2: (head-half x node-parity) fused scores+softmax+pooling ----------------
// 4 waves: wave = (hh = head-half, np = node parity). Wave owns heads
// [4hh,4hh+4) and nodes s+4t+np, s+4t+np+2 (2/iter, double-buffered).
// Full 512-dim row per wave (2 float4/lane). Regs: wk 32 + S 32 + bufs 32
// + temps ~15 = ~110 < 128 cap (launch_bounds(256,2) => empirical cap 128).
// No LDS / no barriers in loop; each row read by the 2 hh-waves (L1/L2 hit).
// Score reduce: two independent 6-op value-paired butterflies (r8-proven).

#define PREF(T, X0, X1, X2, X3)                      \
  {                                                  \
    int i0_ = s + 4 * (T) + np;                      \
    int ia_ = i0_ < em1 ? i0_ : em1;                 \
    int ib_ = i0_ + 2 < em1 ? i0_ + 2 : em1;         \
    size_t oa_ = (size_t)ia_ * 128 + lane;           \
    X0 = emb4[oa_]; X1 = emb4[oa_ + 64];             \
    size_t ob_ = (size_t)ib_ * 128 + lane;           \
    X2 = emb4[ob_]; X3 = emb4[ob_ + 64];             \
  }

#define PROC(T, X0, X1, X2, X3)                                                 \
  {                                                                             \
    float p0[4], p1[4];                                                         \
    _Pragma("unroll")                                                           \
    for (int h = 0; h < 4; ++h) {                                               \
      p0[h] = X0.x * wkA[h].x + X0.y * wkA[h].y + X0.z * wkA[h].z +             \
              X0.w * wkA[h].w + X1.x * wkB[h].x + X1.y * wkB[h].y +             \
              X1.z * wkB[h].z + X1.w * wkB[h].w;                                \
      p1[h] = X2.x * wkA[h].x + X2.y * wkA[h].y + X2.z * wkA[h].z +             \
              X2.w * wkA[h].w + X3.x * wkB[h].x + X3.y * wkB[h].y +             \
              X3.z * wkB[h].z + X3.w * wkB[h].w;                                \
    }                                                                           \
    float q0[2], q1[2];                                                         \
    _Pragma("unroll")                                                           \
    for (int i2 = 0; i2 < 2; ++i2) {                                            \
      float k0 = (lane & 1) ? p0[2 * i2 + 1] : p0[2 * i2];                      \
      float s0 = (lane & 1) ? p0[2 * i2] : p0[2 * i2 + 1];                      \
      q0[i2] = k0 + __shfl_xor(s0, 1);                                          \
      float k1 = (lane & 1) ? p1[2 * i2 + 1] : p1[2 * i2];                      \
      float s1 = (lane & 1) ? p1[2 * i2] : p1[2 * i2 + 1];                      \
      q1[i2] = k1 + __shfl_xor(s1, 1);                                          \
    }                                                                           \
    float r0, r1;                                                               \
    {                                                                           \
      float k0 = (lane & 2) ? q0[1] : q0[0];                                    \
      float s0 = (lane & 2) ? q0[0] : q0[1];                                    \
      r0 = k0 + __shfl_xor(s0, 2);                                              \
      float k1 = (lane & 2) ? q1[1] : q1[0];                                    \
      float s1 = (lane & 2) ? q1[0] : q1[1];                                    \
      r1 = k1 + __shfl_xor(s1, 2);                                              \
    }                                                                           \
    r0 += __shfl_xor(r0, 4);  r1 += __shfl_xor(r1, 4);                          \
    r0 += __shfl_xor(r0, 8);  r1 += __shfl_xor(r1, 8);                          \
    r0 += __shfl_xor(r0, 16); r1 += __shfl_xor(r1, 16);                         \
    r0 += __shfl_xor(r0, 32); r1 += __shfl_xor(r1, 32);                         \
    int n0_ = s + 4 * (T) + np;                                                 \
    float w_0 = (n0_ < e2) ? exp2f(r0 + kbl) : 0.f;                             \
    float w_1 = (n0_ + 2 < e2) ? exp2f(r1 + kbl) : 0.f;                         \
    dn += w_0 + w_1;                                                            \
    float a0 = readlane_f(w_0, 0), a1 = readlane_f(w_0, 1);                     \
    float a2 = readlane_f(w_0, 2), a3 = readlane_f(w_0, 3);                     \
    float b0 = readlane_f(w_1, 0), b1 = readlane_f(w_1, 1);                     \
    float b2 = readlane_f(w_1, 2), b3 = readlane_f(w_1, 3);                     \
    SA[0].x += a0 * X0.x + b0 * X2.x; SA[0].y += a0 * X0.y + b0 * X2.y;         \
    SA[0].z += a0 * X0.z + b0 * X2.z; SA[0].w += a0 * X0.w + b0 * X2.w;         \
    SB[0].x += a0 * X1.x + b0 * X3.x; SB[0].y += a0 * X1.y + b0 * X3.y;         \
    SB[0].z += a0 * X1.z + b0 * X3.z; SB[0].w += a0 * X1.w + b0 * X3.w;         \
    SA[1].x += a1 * X0.x + b1 * X2.x; SA[1].y += a1 * X0.y + b1 * X2.y;         \
    SA[1].z += a1 * X0.z + b1 * X2.z; SA[1].w += a1 * X0.w + b1 * X2.w;         \
    SB[1].x += a1 * X1.x + b1 * X3.x; SB[1].y += a1 * X1.y + b1 * X3.y;         \
    SB[1].z += a1 * X1.z + b1 * X3.z; SB[1].w += a1 * X1.w + b1 * X3.w;         \
    SA[2].x += a2 * X0.x + b2 * X2.x; SA[2].y += a2 * X0.y + b2 * X2.y;         \
    SA[2].z += a2 * X0.z + b2 * X2.z; SA[2].w += a2 * X0.w + b2 * X2.w;         \
    SB[2].x += a2 * X1.x + b2 * X3.x; SB[2].y += a2 * X1.y + b2 * X3.y;         \
    SB[2].z += a2 * X1.z + b2 * X3.z; SB[2].w += a2 * X1.w + b2 * X3.w;         \
    SA[3].x += a3 * X0.x + b3 * X2.x; SA[3].y += a3 * X0.y + b3 * X2.y;         \
    SA[3].z += a3 * X0.z + b3 * X2.z; SA[3].w += a3 * X0.w + b3 * X2.w;         \
    SB[3].x += a3 * X1.x + b3 * X3.x; SB[3].y += a3 * X1.y + b3 * X3.y;         \
    SB[3].z += a3 * X1.z + b3 * X3.z; SB[3].w += a3 * X1.w + b3 * X3.w;         \
  }

__global__ __launch_bounds__(256, 2) void k_main(const float* __restrict__ emb,
                                                 const int* __restrict__ seg,
                                                 const float* __restrict__ wk,
                                                 const float* __restrict__ kb,
                                                 unsigned short* __restrict__ S_out,
                                                 int reps) {
  __shared__ float ep[4][2048];   // 32 KB epilogue combine
  __shared__ float dnl[4][4];     // [wave][local head]

  const int tid = threadIdx.x;
  const int lane = tid & 63, wave = tid >> 6;
  const int hh = wave >> 1, np = wave & 1;
  const int b = blockIdx.x;
  const int s = seg[b], e2 = seg[b + 1];
  const int nt = e2 - s, em1 = e2 - 1;
  const int it = (nt + 3) >> 2;

  float4 wkA[4], wkB[4];
  #pragma unroll
  for (int h = 0; h < 4; ++h) {
    wkA[h] = *(const float4*)(wk + (hh * 4 + h) * 512 + 4 * lane);
    wkB[h] = *(const float4*)(wk + (hh * 4 + h) * 512 + 256 + 4 * lane);
  }
  const float kbl = kb[hh * 4 + (lane & 3)];
  const float4* emb4 = (const float4*)emb;

  for (int rep = 0; rep < reps; ++rep) {
    float4 SA[4], SB[4];
    #pragma unroll
    for (int h = 0; h < 4; ++h) {
      SA[h] = make_float4(0.f, 0.f, 0.f, 0.f);
      SB[h] = make_float4(0.f, 0.f, 0.f, 0.f);
    }
    float dn = 0.f;

    if (it > 0) {
      float4 A0, A1, A2, A3, B0, B1, B2, B3;
      PREF(0, A0, A1, A2, A3);
      int t = 0;
      while (true) {
        PREF(t + 1, B0, B1, B2, B3);
        PROC(t, A0, A1, A2, A3);
        ++t; if (t >= it) break;
        PREF(t + 1, A0, A1, A2, A3);
        PROC(t, B0, B1, B2, B3);
        ++t; if (t >= it) break;
      }
    }

    // ---- epilogue: combine the two node-parity waves per head-half ----
    __syncthreads();   // also guards ep reuse across reps
    #pragma unroll
    for (int h = 0; h < 4; ++h) {
      *(float4*)&ep[wave][h * 512 + 4 * lane] = SA[h];
      *(float4*)&ep[wave][h * 512 + 256 + 4 * lane] = SB[h];
    }
    if (lane < 4) dnl[wave][lane] = dn;   // lane l holds head hh*4+l's denom
    __syncthreads();

    const int head = tid >> 5, j = tid & 31;     // 8 heads x 32 chunks
    const int hh2 = head >> 2, hl = head & 3;
    const int d0 = j * 16;
    float d = dnl[2 * hh2][hl] + dnl[2 * hh2 + 1][hl];
    float invd = d > 0.f ? 1.f / d : 0.f;
    const float* pa = &ep[2 * hh2][hl * 512 + d0];
    const float* pb = &ep[2 * hh2 + 1][hl * 512 + d0];
    unsigned short* po = S_out + ((size_t)head * 4096 + b) * 512 + d0;
    float v[16];
    #pragma unroll
    for (int k = 0; k < 16; ++k) v[k] = (pa[k] + pb[k]) * invd;
    uint4 o0, o1;
    o0.x = pack2(v[0], v[1]);   o0.y = pack2(v[2], v[3]);
    o0.z = pack2(v[4], v[5]);   o0.w = pack2(v[6], v[7]);
    o1.x = pack2(v[8], v[9]);   o1.y = pack2(v[10], v[11]);
    o1.z = pack2(v[12], v[13]); o1.w = pack2(v[14], v[15]);
    *(uint4*)po = o0;
    *(uint4*)(po + 8) = o1;
  }
}

// ---------------- K3/K4: MFMA NT GEMM ----------------
template <bool C_BF16>
__global__ __launch_bounds__(256) void k_gemm_mfma(
    const unsigned short* __restrict__ A, size_t a_cb_stride,
    const unsigned short* __restrict__ Whi, const unsigned short* __restrict__ Wlo,
    const float* __restrict__ bias, void* __restrict__ Cv) {
  const int t = threadIdx.x;
  const int lane = t & 63, wvid = t >> 6;
  const int wr = wvid >> 1, wc = wvid & 1;
  const int row16 = lane & 15;
  const int k8 = (lane >> 4) * 8;
  const int mbase = blockIdx.x * 64 + wr * 32;
  const int nbase = blockIdx.y * 64 + wc * 32;

  const unsigned short* Ap = A + (size_t)blockIdx.y * a_cb_stride +
                             (size_t)(mbase + row16) * 512 + k8;
  const unsigned short* Wh = Whi + (size_t)(nbase + row16) * 512 + k8;
  const unsigned short* Wl = Wlo + (size_t)(nbase + row16) * 512 + k8;

  f32x4 acc[2][2] = {};

  #pragma unroll 4
  for (int kk = 0; kk < 512; kk += 32) {
    bf16x8 a0 = *(const bf16x8*)(Ap + kk);
    bf16x8 a1 = *(const bf16x8*)(Ap + 16 * 512 + kk);
    bf16x8 h0 = *(const bf16x8*)(Wh + kk);
    bf16x8 h1 = *(const bf16x8*)(Wh + 16 * 512 + kk);
    bf16x8 l0 = *(const bf16x8*)(Wl + kk);
    bf16x8 l1 = *(const bf16x8*)(Wl + 16 * 512 + kk);
    acc[0][0] = __builtin_amdgcn_mfma_f32_16x16x32_bf16(a0, h0, acc[0][0], 0, 0, 0);
    acc[0][1] = __builtin_amdgcn_mfma_f32_16x16x32_bf16(a0, h1, acc[0][1], 0, 0, 0);
    acc[1][0] = __builtin_amdgcn_mfma_f32_16x16x32_bf16(a1, h0, acc[1][0], 0, 0, 0);
    acc[1][1] = __builtin_amdgcn_mfma_f32_16x16x32_bf16(a1, h1, acc[1][1], 0, 0, 0);
    acc[0][0] = __builtin_amdgcn_mfma_f32_16x16x32_bf16(a0, l0, acc[0][0], 0, 0, 0);
    acc[0][1] = __builtin_amdgcn_mfma_f32_16x16x32_bf16(a0, l1, acc[0][1], 0, 0, 0);
    acc[1][0] = __builtin_amdgcn_mfma_f32_16x16x32_bf16(a1, l0, acc[1][0], 0, 0, 0);
    acc[1][1] = __builtin_amdgcn_mfma_f32_16x16x32_bf16(a1, l1, acc[1][1], 0, 0, 0);
  }

  const int r4 = (lane >> 4) * 4;
  #pragma unroll
  for (int c = 0; c < 2; ++c) {
    const float bc = bias[nbase + c * 16 + row16];
    #pragma unroll
    for (int r = 0; r < 2; ++r) {
      #pragma unroll
      for (int j = 0; j < 4; ++j) {
        float v = acc[r][c][j] + bc;
        size_t row = (size_t)(mbase + r * 16 + r4 + j);
        size_t col = (size_t)(nbase + c * 16 + row16);
        if (C_BF16)
          ((unsigned short*)Cv)[row * 512 + col] = f2bf(v);
        else
          ((float*)Cv)[row * 512 + col] = v;
      }
    }
  }
}

// ---------------- launcher ----------------
extern "C" void kernel_launch(void* const* d_in, const int* in_sizes, int n_in,
                              void* d_out, int out_size, void* d_ws, size_t ws_size,
                              hipStream_t stream) {
  const float* emb   = (const float*)d_in[0];
  const void*  batch = d_in[1];
  const float* qry   = (const float*)d_in[2];
  const float* Wq    = (const float*)d_in[3];
  const float* bq    = (const float*)d_in[4];
  const float* Wk    = (const float*)d_in[5];
  const float* bk    = (const float*)d_in[6];
  const float* Wv    = (const float*)d_in[7];
  const float* bv    = (const float*)d_in[8];
  const float* Wo    = (const float*)d_in[9];
  const float* bo    = (const float*)d_in[10];
  const int N = in_sizes[1];

  if (ws_size < WS_NEEDED) return;

  char* ws = (char*)d_ws;
  float* wk_eff = (float*)(ws + WK_OFF);
  float* kbias  = (float*)(ws + KB_OFF);
  float* q2     = (float*)(ws + Q2_OFF);
  int*   seg    = (int*)(ws + SEG_OFF);
  unsigned short* S_ws = (unsigned short*)(ws + S_OFF);
  unsigned short* attn = (unsigned short*)(ws + ATTN_OFF);
  unsigned short* wvhi = (unsigned short*)(ws + WVHI_OFF);
  unsigned short* wvlo = (unsigned short*)(ws + WVLO_OFF);
  unsigned short* wohi = (unsigned short*)(ws + WOHI_OFF);
  unsigned short* wolo = (unsigned short*)(ws + WOLO_OFF);

  k_prep<<<1043, 256, 0, stream>>>(Wv, Wo, wvhi, wvlo, wohi, wolo,
                                   batch, N, seg, qry, Wq, bq, q2);
  k_wk  <<<17, 256, 0, stream>>>(Wk, bk, q2, wk_eff, kbias);
  k_main<<<4096, 256, 0, stream>>>(emb, seg, wk_eff, kbias, S_ws, 1);

  // ---- PROBE: one dispatch, 4 internal reps into scratch. Surfaces in
  // rocprof top-5 with k_main's true VGPR/WRITE_SIZE (spill check) and BW.
  if (ws_size >= WS_PROBE) {
    unsigned short* S_dup = (unsigned short*)(ws + SDUP_OFF);
    k_main<<<4096, 256, 0, stream>>>(emb, seg, wk_eff, kbias, S_dup, 4);
  }

  dim3 g(64, 8);
  k_gemm_mfma<true ><<<g, 256, 0, stream>>>(S_ws, (size_t)4096 * 512, wvhi, wvlo, bv, attn);
  k_gemm_mfma<false><<<g, 256, 0, stream>>>(attn, 0, wohi, wolo, bo, d_out);
}

// Round 11
// 1182.158 us; speedup vs baseline: 7.7111x; 1.0146x over previous
//
#include <hip/hip_runtime.h>

#define LOG2E 1.4426950408889634f

// ---------------- ws layout (bytes) ----------------
#define WK_OFF   ((size_t)0)          // wk_eff f32 [8][512]
#define KB_OFF   ((size_t)16384)      // kbias f32 [8]
#define Q2_OFF   ((size_t)16416)      // q2 f32 [512]
#define SEG_OFF  ((size_t)18464)      // seg i32 [4097]
#define S_OFF    ((size_t)34880)      // S_ws bf16 [8][4096][512]
#define ATTN_OFF ((size_t)33589312)   // attn bf16 [4096][512]
#define WVHI_OFF ((size_t)37783616)   // Wv hi bf16 [512*512]
#define WVLO_OFF ((size_t)38307904)
#define WOHI_OFF ((size_t)38832192)
#define WOLO_OFF ((size_t)39356480)
#define WS_NEEDED ((size_t)39880768)
// probe: duplicate k_main output region (32 MB)
#define SDUP_OFF ((size_t)39880768)
#define WS_PROBE (SDUP_OFF + (size_t)8*4096*512*2)

typedef __bf16 bf16x8 __attribute__((ext_vector_type(8)));
typedef float f32x4 __attribute__((ext_vector_type(4)));
typedef float f32x2 __attribute__((ext_vector_type(2)));

__device__ __forceinline__ float readlane_f(float v, int l) {
  return __int_as_float(__builtin_amdgcn_readlane(__float_as_int(v), l));
}

__device__ __forceinline__ unsigned short f2bf(float x) {
  unsigned u = __float_as_uint(x);
  unsigned r = (u + 0x7fffu + ((u >> 16) & 1u)) >> 16;
  return (unsigned short)r;
}

__device__ __forceinline__ unsigned pack2(float x, float y) {
  return (unsigned)f2bf(x) | ((unsigned)f2bf(y) << 16);
}

__device__ __forceinline__ float bf2f(unsigned short h) {
  return __uint_as_float((unsigned)h << 16);
}

// packed f32 math (VOP3P): 2 FLOP per issue slot
__device__ __forceinline__ void pk_fma_acc(f32x2& acc, f32x2 a, f32x2 b) {
  asm("v_pk_fma_f32 %0, %1, %2, %0" : "+v"(acc) : "v"(a), "v"(b));
}
__device__ __forceinline__ f32x2 pk_mul(f32x2 a, f32x2 b) {
  f32x2 d;
  asm("v_pk_mul_f32 %0, %1, %2" : "=v"(d) : "v"(a), "v"(b));
  return d;
}

// ---------------- K0: fused prep (W hi/lo split + seg lower_bound + q2) ----------------
__global__ __launch_bounds__(256) void k_prep(
    const float* __restrict__ Wv, const float* __restrict__ Wo,
    unsigned short* __restrict__ wvhi, unsigned short* __restrict__ wvlo,
    unsigned short* __restrict__ wohi, unsigned short* __restrict__ wolo,
    const void* __restrict__ batch, int n, int* __restrict__ seg,
    const float* __restrict__ qry, const float* __restrict__ Wq,
    const float* __restrict__ bq, float* __restrict__ q2) {
  int bx = blockIdx.x;
  if (bx < 1024) {
    int i = bx * 256 + threadIdx.x;
    float v = Wv[i];
    unsigned short h = f2bf(v);
    wvhi[i] = h;
    wvlo[i] = f2bf(v - bf2f(h));
    float o = Wo[i];
    unsigned short h2 = f2bf(o);
    wohi[i] = h2;
    wolo[i] = f2bf(o - bf2f(h2));
  } else if (bx < 1041) {
    int b = (bx - 1024) * 256 + threadIdx.x;
    if (b > 4096) return;
    const int* b32 = (const int*)batch;
    const long long* b64 = (const long long*)batch;
    bool is64 = (b32[n - 1] == 0);
    int lo = 0, hi = n;
    while (lo < hi) {
      int mid = (lo + hi) >> 1;
      long long v = is64 ? b64[mid] : (long long)b32[mid];
      if (v < (long long)b) lo = mid + 1; else hi = mid;
    }
    seg[b] = lo;
  } else {
    int d = (bx - 1041) * 256 + threadIdx.x;
    const float4* q4 = (const float4*)qry;
    const float4* w4 = (const float4*)(Wq + (size_t)d * 512);
    float acc = 0.f;
    #pragma unroll 4
    for (int j = 0; j < 128; ++j) {
      float4 a = q4[j], b = w4[j];
      acc += a.x * b.x + a.y * b.y + a.z * b.z + a.w * b.w;
    }
    q2[d] = (acc + bq[d]) * (0.125f * LOG2E);
  }
}

// ---------------- K1: wk_eff + kbias ----------------
__global__ __launch_bounds__(256) void k_wk(const float* __restrict__ Wk,
                                            const float* __restrict__ bk,
                                            const float* __restrict__ q2,
                                            float* __restrict__ wk,
                                            float* __restrict__ kb) {
  if (blockIdx.x == 16) {
    int h = threadIdx.x;
    if (h < 8) {
      float acc = 0.f;
      for (int dd = 0; dd < 64; ++dd) acc += q2[h * 64 + dd] * bk[h * 64 + dd];
      kb[h] = acc;
    }
    return;
  }
  int id = blockIdx.x * 256 + threadIdx.x;
  int h = id >> 9, e = id & 511;
  float acc = 0.f;
  #pragma unroll 4
  for (int dd = 0; dd < 64; ++dd)
    acc += q2[h * 64 + dd] * Wk[(size_t)(h * 64 + dd) * 512 + e];
  wk[id] = acc;
}

// ---------------- K2: (head-half x node-parity), packed-f32, 1-exp2 butterfly ----------------
// 4 waves: wave = (hh = head-half, np = node parity). Wave owns heads
// [4hh,4hh+4) and nodes s+4t+np, s+4t+np+2. All hot FMA as v_pk_fma_f32.
// Reduce: value-paired butterfly merges the 8 (head,node) partials to ONE
// value/lane by xor4, so xor8/16/32 (the DS-pipe stages) run once per 2 nodes
// and one exp2 serves both nodes. Slot at lane l&7: h=2*bit2+bit1, n=bit0.

#define PREF(T, X0, X1, X2, X3)                      \
  {                                                  \
    int i0_ = s + 4 * (T) + np;                      \
    int ia_ = i0_ < em1 ? i0_ : em1;                 \
    int ib_ = i0_ + 2 < em1 ? i0_ + 2 : em1;         \
    size_t oa_ = (size_t)ia_ * 128 + lane;           \
    X0 = emb4[oa_]; X1 = emb4[oa_ + 64];             \
    size_t ob_ = (size_t)ib_ * 128 + lane;           \
    X2 = emb4[ob_]; X3 = emb4[ob_ + 64];             \
  }

#define PROC(T, X0, X1, X2, X3)                                                 \
  {                                                                             \
    float pp[8];                                                                \
    _Pragma("unroll")                                                           \
    for (int h = 0; h < 4; ++h) {                                               \
      f32x2 pa = pk_mul(X0.xy, wkA[h].xy);                                      \
      pk_fma_acc(pa, X0.zw, wkA[h].zw);                                         \
      pk_fma_acc(pa, X1.xy, wkB[h].xy);                                         \
      pk_fma_acc(pa, X1.zw, wkB[h].zw);                                         \
      f32x2 pb = pk_mul(X2.xy, wkA[h].xy);                                      \
      pk_fma_acc(pb, X2.zw, wkA[h].zw);                                         \
      pk_fma_acc(pb, X3.xy, wkB[h].xy);                                         \
      pk_fma_acc(pb, X3.zw, wkB[h].zw);                                         \
      pp[2 * h] = pa.x + pa.y;                                                  \
      pp[2 * h + 1] = pb.x + pb.y;                                              \
    }                                                                           \
    float q[4];                                                                 \
    _Pragma("unroll")                                                           \
    for (int h = 0; h < 4; ++h) {                                               \
      float keep = (lane & 1) ? pp[2 * h + 1] : pp[2 * h];                      \
      float send = (lane & 1) ? pp[2 * h] : pp[2 * h + 1];                      \
      q[h] = keep + __shfl_xor(send, 1);                                        \
    }                                                                           \
    float r[2];                                                                 \
    _Pragma("unroll")                                                           \
    for (int j = 0; j < 2; ++j) {                                               \
      float keep = (lane & 2) ? q[2 * j + 1] : q[2 * j];                        \
      float send = (lane & 2) ? q[2 * j] : q[2 * j + 1];                        \
      r[j] = keep + __shfl_xor(send, 2);                                        \
    }                                                                           \
    float sv;                                                                   \
    {                                                                           \
      float keep = (lane & 4) ? r[1] : r[0];                                    \
      float send = (lane & 4) ? r[0] : r[1];                                    \
      sv = keep + __shfl_xor(send, 4);                                          \
    }                                                                           \
    sv += __shfl_xor(sv, 8);                                                    \
    sv += __shfl_xor(sv, 16);                                                   \
    sv += __shfl_xor(sv, 32);                                                   \
    int idxl = s + 4 * (T) + np + 2 * (lane & 1);                               \
    float ex = exp2f(sv + kbsel);                                               \
    float wgt = (idxl < e2) ? ex : 0.f;                                         \
    dn += wgt;                                                                  \
    float a0 = readlane_f(wgt, 0), b0 = readlane_f(wgt, 1);                     \
    float a1 = readlane_f(wgt, 2), b1 = readlane_f(wgt, 3);                     \
    float a2 = readlane_f(wgt, 4), b2 = readlane_f(wgt, 5);                     \
    float a3 = readlane_f(wgt, 6), b3 = readlane_f(wgt, 7);                     \
    f32x2 va0 = {a0, a0}, vb0 = {b0, b0};                                       \
    f32x2 va1 = {a1, a1}, vb1 = {b1, b1};                                       \
    f32x2 va2 = {a2, a2}, vb2 = {b2, b2};                                       \
    f32x2 va3 = {a3, a3}, vb3 = {b3, b3};                                       \
    pk_fma_acc(SAlo[0], X0.xy, va0); pk_fma_acc(SAlo[0], X2.xy, vb0);           \
    pk_fma_acc(SAhi[0], X0.zw, va0); pk_fma_acc(SAhi[0], X2.zw, vb0);           \
    pk_fma_acc(SBlo[0], X1.xy, va0); pk_fma_acc(SBlo[0], X3.xy, vb0);           \
    pk_fma_acc(SBhi[0], X1.zw, va0); pk_fma_acc(SBhi[0], X3.zw, vb0);           \
    pk_fma_acc(SAlo[1], X0.xy, va1); pk_fma_acc(SAlo[1], X2.xy, vb1);           \
    pk_fma_acc(SAhi[1], X0.zw, va1); pk_fma_acc(SAhi[1], X2.zw, vb1);           \
    pk_fma_acc(SBlo[1], X1.xy, va1); pk_fma_acc(SBlo[1], X3.xy, vb1);           \
    pk_fma_acc(SBhi[1], X1.zw, va1); pk_fma_acc(SBhi[1], X3.zw, vb1);           \
    pk_fma_acc(SAlo[2], X0.xy, va2); pk_fma_acc(SAlo[2], X2.xy, vb2);           \
    pk_fma_acc(SAhi[2], X0.zw, va2); pk_fma_acc(SAhi[2], X2.zw, vb2);           \
    pk_fma_acc(SBlo[2], X1.xy, va2); pk_fma_acc(SBlo[2], X3.xy, vb2);           \
    pk_fma_acc(SBhi[2], X1.zw, va2); pk_fma_acc(SBhi[2], X3.zw, vb2);           \
    pk_fma_acc(SAlo[3], X0.xy, va3); pk_fma_acc(SAlo[3], X2.xy, vb3);           \
    pk_fma_acc(SAhi[3], X0.zw, va3); pk_fma_acc(SAhi[3], X2.zw, vb3);           \
    pk_fma_acc(SBlo[3], X1.xy, va3); pk_fma_acc(SBlo[3], X3.xy, vb3);           \
    pk_fma_acc(SBhi[3], X1.zw, va3); pk_fma_acc(SBhi[3], X3.zw, vb3);           \
  }

__global__ __launch_bounds__(256, 2) void k_main(const float* __restrict__ emb,
                                                 const int* __restrict__ seg,
                                                 const float* __restrict__ wk,
                                                 const float* __restrict__ kb,
                                                 unsigned short* __restrict__ S_out,
                                                 int reps) {
  __shared__ float ep[4][2048];   // 32 KB epilogue combine
  __shared__ float dnl[4][8];     // [wave][slot]

  const int tid = threadIdx.x;
  const int lane = tid & 63, wave = tid >> 6;
  const int hh = wave >> 1, np = wave & 1;
  const int b = blockIdx.x;
  const int s = seg[b], e2 = seg[b + 1];
  const int nt = e2 - s, em1 = e2 - 1;
  const int it = (nt + 3) >> 2;

  f32x4 wkA[4], wkB[4];
  #pragma unroll
  for (int h = 0; h < 4; ++h) {
    wkA[h] = *(const f32x4*)(wk + (hh * 4 + h) * 512 + 4 * lane);
    wkB[h] = *(const f32x4*)(wk + (hh * 4 + h) * 512 + 256 + 4 * lane);
  }
  // slot at lane: h = 2*bit2 + bit1, n = bit0
  const float kbsel = kb[hh * 4 + 2 * ((lane >> 2) & 1) + ((lane >> 1) & 1)];
  const f32x4* emb4 = (const f32x4*)emb;
  const f32x2 Z2 = {0.f, 0.f};

  for (int rep = 0; rep < reps; ++rep) {
    f32x2 SAlo[4], SAhi[4], SBlo[4], SBhi[4];
    #pragma unroll
    for (int h = 0; h < 4; ++h) {
      SAlo[h] = Z2; SAhi[h] = Z2; SBlo[h] = Z2; SBhi[h] = Z2;
    }
    float dn = 0.f;

    if (it > 0) {
      f32x4 A0, A1, A2, A3, B0, B1, B2, B3;
      PREF(0, A0, A1, A2, A3);
      int t = 0;
      while (true) {
        PREF(t + 1, B0, B1, B2, B3);
        PROC(t, A0, A1, A2, A3);
        ++t; if (t >= it) break;
        PREF(t + 1, A0, A1, A2, A3);
        PROC(t, B0, B1, B2, B3);
        ++t; if (t >= it) break;
      }
    }

    // ---- epilogue: combine the two node-parity waves per head-half ----
    __syncthreads();   // also guards ep reuse across reps
    #pragma unroll
    for (int h = 0; h < 4; ++h) {
      f32x4 tA, tB;
      tA.xy = SAlo[h]; tA.zw = SAhi[h];
      tB.xy = SBlo[h]; tB.zw = SBhi[h];
      *(f32x4*)&ep[wave][h * 512 + 4 * lane] = tA;
      *(f32x4*)&ep[wave][h * 512 + 256 + 4 * lane] = tB;
    }
    if (lane < 8) dnl[wave][lane] = dn;
    __syncthreads();

    const int head = tid >> 5, j = tid & 31;     // 8 heads x 32 chunks
    const int hh2 = head >> 2, hl = head & 3;
    const int l0 = 2 * (hl & 1) + 4 * (hl >> 1); // slot lane for (hl, n=0)
    const int d0 = j * 16;
    float d = dnl[2 * hh2][l0] + dnl[2 * hh2][l0 + 1] +
              dnl[2 * hh2 + 1][l0] + dnl[2 * hh2 + 1][l0 + 1];
    float invd = d > 0.f ? 1.f / d : 0.f;
    const float* pa = &ep[2 * hh2][hl * 512 + d0];
    const float* pb = &ep[2 * hh2 + 1][hl * 512 + d0];
    unsigned short* po = S_out + ((size_t)head * 4096 + b) * 512 + d0;
    float v[16];
    #pragma unroll
    for (int k = 0; k < 16; ++k) v[k] = (pa[k] + pb[k]) * invd;
    uint4 o0, o1;
    o0.x = pack2(v[0], v[1]);   o0.y = pack2(v[2], v[3]);
    o0.z = pack2(v[4], v[5]);   o0.w = pack2(v[6], v[7]);
    o1.x = pack2(v[8], v[9]);   o1.y = pack2(v[10], v[11]);
    o1.z = pack2(v[12], v[13]); o1.w = pack2(v[14], v[15]);
    *(uint4*)po = o0;
    *(uint4*)(po + 8) = o1;
  }
}

// ---------------- K3/K4: MFMA NT GEMM ----------------
template <bool C_BF16>
__global__ __launch_bounds__(256) void k_gemm_mfma(
    const unsigned short* __restrict__ A, size_t a_cb_stride,
    const unsigned short* __restrict__ Whi, const unsigned short* __restrict__ Wlo,
    const float* __restrict__ bias, void* __restrict__ Cv) {
  const int t = threadIdx.x;
  const int lane = t & 63, wvid = t >> 6;
  const int wr = wvid >> 1, wc = wvid & 1;
  const int row16 = lane & 15;
  const int k8 = (lane >> 4) * 8;
  const int mbase = blockIdx.x * 64 + wr * 32;
  const int nbase = blockIdx.y * 64 + wc * 32;

  const unsigned short* Ap = A + (size_t)blockIdx.y * a_cb_stride +
                             (size_t)(mbase + row16) * 512 + k8;
  const unsigned short* Wh = Whi + (size_t)(nbase + row16) * 512 + k8;
  const unsigned short* Wl = Wlo + (size_t)(nbase + row16) * 512 + k8;

  f32x4 acc[2][2] = {};

  #pragma unroll 4
  for (int kk = 0; kk < 512; kk += 32) {
    bf16x8 a0 = *(const bf16x8*)(Ap + kk);
    bf16x8 a1 = *(const bf16x8*)(Ap + 16 * 512 + kk);
    bf16x8 h0 = *(const bf16x8*)(Wh + kk);
    bf16x8 h1 = *(const bf16x8*)(Wh + 16 * 512 + kk);
    bf16x8 l0 = *(const bf16x8*)(Wl + kk);
    bf16x8 l1 = *(const bf16x8*)(Wl + 16 * 512 + kk);
    acc[0][0] = __builtin_amdgcn_mfma_f32_16x16x32_bf16(a0, h0, acc[0][0], 0, 0, 0);
    acc[0][1] = __builtin_amdgcn_mfma_f32_16x16x32_bf16(a0, h1, acc[0][1], 0, 0, 0);
    acc[1][0] = __builtin_amdgcn_mfma_f32_16x16x32_bf16(a1, h0, acc[1][0], 0, 0, 0);
    acc[1][1] = __builtin_amdgcn_mfma_f32_16x16x32_bf16(a1, h1, acc[1][1], 0, 0, 0);
    acc[0][0] = __builtin_amdgcn_mfma_f32_16x16x32_bf16(a0, l0, acc[0][0], 0, 0, 0);
    acc[0][1] = __builtin_amdgcn_mfma_f32_16x16x32_bf16(a0, l1, acc[0][1], 0, 0, 0);
    acc[1][0] = __builtin_amdgcn_mfma_f32_16x16x32_bf16(a1, l0, acc[1][0], 0, 0, 0);
    acc[1][1] = __builtin_amdgcn_mfma_f32_16x16x32_bf16(a1, l1, acc[1][1], 0, 0, 0);
  }

  const int r4 = (lane >> 4) * 4;
  #pragma unroll
  for (int c = 0; c < 2; ++c) {
    const float bc = bias[nbase + c * 16 + row16];
    #pragma unroll
    for (int r = 0; r < 2; ++r) {
      #pragma unroll
      for (int j = 0; j < 4; ++j) {
        float v = acc[r][c][j] + bc;
        size_t row = (size_t)(mbase + r * 16 + r4 + j);
        size_t col = (size_t)(nbase + c * 16 + row16);
        if (C_BF16)
          ((unsigned short*)Cv)[row * 512 + col] = f2bf(v);
        else
          ((float*)Cv)[row * 512 + col] = v;
      }
    }
  }
}

// ---------------- launcher ----------------
extern "C" void kernel_launch(void* const* d_in, const int* in_sizes, int n_in,
                              void* d_out, int out_size, void* d_ws, size_t ws_size,
                              hipStream_t stream) {
  const float* emb   = (const float*)d_in[0];
  const void*  batch = d_in[1];
  const float* qry   = (const float*)d_in[2];
  const float* Wq    = (const float*)d_in[3];
  const float* bq    = (const float*)d_in[4];
  const float* Wk    = (const float*)d_in[5];
  const float* bk    = (const float*)d_in[6];
  const float* Wv    = (const float*)d_in[7];
  const float* bv    = (const float*)d_in[8];
  const float* Wo    = (const float*)d_in[9];
  const float* bo    = (const float*)d_in[10];
  const int N = in_sizes[1];

  if (ws_size < WS_NEEDED) return;

  char* ws = (char*)d_ws;
  float* wk_eff = (float*)(ws + WK_OFF);
  float* kbias  = (float*)(ws + KB_OFF);
  float* q2     = (float*)(ws + Q2_OFF);
  int*   seg    = (int*)(ws + SEG_OFF);
  unsigned short* S_ws = (unsigned short*)(ws + S_OFF);
  unsigned short* attn = (unsigned short*)(ws + ATTN_OFF);
  unsigned short* wvhi = (unsigned short*)(ws + WVHI_OFF);
  unsigned short* wvlo = (unsigned short*)(ws + WVLO_OFF);
  unsigned short* wohi = (unsigned short*)(ws + WOHI_OFF);
  unsigned short* wolo = (unsigned short*)(ws + WOLO_OFF);

  k_prep<<<1043, 256, 0, stream>>>(Wv, Wo, wvhi, wvlo, wohi, wolo,
                                   batch, N, seg, qry, Wq, bq, q2);
  k_wk  <<<17, 256, 0, stream>>>(Wk, bk, q2, wk_eff, kbias);
  k_main<<<4096, 256, 0, stream>>>(emb, seg, wk_eff, kbias, S_ws, 1);

  // ---- PROBE: one dispatch, 4 internal reps into scratch. Surfaces in
  // rocprof top-5 with k_main's true VGPR/WRITE_SIZE (spill check) and BW.
  if (ws_size >= WS_PROBE) {
    unsigned short* S_dup = (unsigned short*)(ws + SDUP_OFF);
    k_main<<<4096, 256, 0, stream>>>(emb, seg, wk_eff, kbias, S_dup, 4);
  }

  dim3 g(64, 8);
  k_gemm_mfma<true ><<<g, 256, 0, stream>>>(S_ws, (size_t)4096 * 512, wvhi, wvlo, bv, attn);
  k_gemm_mfma<false><<<g, 256, 0, stream>>>(attn, 0, wohi, wolo, bo, d_out);
}

// Round 12
// 356.051 us; speedup vs baseline: 25.6022x; 3.3202x over previous
//
#include <hip/hip_runtime.h>

#define LOG2E 1.4426950408889634f

// ---------------- ws layout (bytes) ----------------
#define WK_OFF   ((size_t)0)          // wk_eff f32 [8][512]
#define KB_OFF   ((size_t)16384)      // kbias f32 [8]
#define Q2_OFF   ((size_t)16416)      // q2 f32 [512]
#define SEG_OFF  ((size_t)18464)      // seg i32 [4097]
#define S_OFF    ((size_t)34880)      // S_ws bf16 [8][4096][512]
#define ATTN_OFF ((size_t)33589312)   // attn bf16 [4096][512]
#define WVHI_OFF ((size_t)37783616)   // Wv hi bf16 [512*512]
#define WVLO_OFF ((size_t)38307904)
#define WOHI_OFF ((size_t)38832192)
#define WOLO_OFF ((size_t)39356480)
#define WS_NEEDED ((size_t)39880768)

typedef __bf16 bf16x8 __attribute__((ext_vector_type(8)));
typedef float f32x4 __attribute__((ext_vector_type(4)));
typedef float f32x2 __attribute__((ext_vector_type(2)));

__device__ __forceinline__ float readlane_f(float v, int l) {
  return __int_as_float(__builtin_amdgcn_readlane(__float_as_int(v), l));
}

__device__ __forceinline__ unsigned short f2bf(float x) {
  unsigned u = __float_as_uint(x);
  unsigned r = (u + 0x7fffu + ((u >> 16) & 1u)) >> 16;
  return (unsigned short)r;
}

__device__ __forceinline__ unsigned pack2(float x, float y) {
  return (unsigned)f2bf(x) | ((unsigned)f2bf(y) << 16);
}

__device__ __forceinline__ float bf2f(unsigned short h) {
  return __uint_as_float((unsigned)h << 16);
}

// packed f32 math (VOP3P): 2 FLOP per issue slot
__device__ __forceinline__ void pk_fma_acc(f32x2& acc, f32x2 a, f32x2 b) {
  asm("v_pk_fma_f32 %0, %1, %2, %0" : "+v"(acc) : "v"(a), "v"(b));
}
__device__ __forceinline__ f32x2 pk_mul(f32x2 a, f32x2 b) {
  f32x2 d;
  asm("v_pk_mul_f32 %0, %1, %2" : "=v"(d) : "v"(a), "v"(b));
  return d;
}

// ---------------- K0: fused prep (W hi/lo split + seg lower_bound + q2) ----------------
__global__ __launch_bounds__(256) void k_prep(
    const float* __restrict__ Wv, const float* __restrict__ Wo,
    unsigned short* __restrict__ wvhi, unsigned short* __restrict__ wvlo,
    unsigned short* __restrict__ wohi, unsigned short* __restrict__ wolo,
    const void* __restrict__ batch, int n, int* __restrict__ seg,
    const float* __restrict__ qry, const float* __restrict__ Wq,
    const float* __restrict__ bq, float* __restrict__ q2) {
  int bx = blockIdx.x;
  if (bx < 1024) {
    int i = bx * 256 + threadIdx.x;
    float v = Wv[i];
    unsigned short h = f2bf(v);
    wvhi[i] = h;
    wvlo[i] = f2bf(v - bf2f(h));
    float o = Wo[i];
    unsigned short h2 = f2bf(o);
    wohi[i] = h2;
    wolo[i] = f2bf(o - bf2f(h2));
  } else if (bx < 1041) {
    int b = (bx - 1024) * 256 + threadIdx.x;
    if (b > 4096) return;
    const int* b32 = (const int*)batch;
    const long long* b64 = (const long long*)batch;
    bool is64 = (b32[n - 1] == 0);
    int lo = 0, hi = n;
    while (lo < hi) {
      int mid = (lo + hi) >> 1;
      long long v = is64 ? b64[mid] : (long long)b32[mid];
      if (v < (long long)b) lo = mid + 1; else hi = mid;
    }
    seg[b] = lo;
  } else {
    int d = (bx - 1041) * 256 + threadIdx.x;
    const float4* q4 = (const float4*)qry;
    const float4* w4 = (const float4*)(Wq + (size_t)d * 512);
    float acc = 0.f;
    #pragma unroll 4
    for (int j = 0; j < 128; ++j) {
      float4 a = q4[j], b = w4[j];
      acc += a.x * b.x + a.y * b.y + a.z * b.z + a.w * b.w;
    }
    q2[d] = (acc + bq[d]) * (0.125f * LOG2E);
  }
}

// ---------------- K1: wk_eff + kbias ----------------
__global__ __launch_bounds__(256) void k_wk(const float* __restrict__ Wk,
                                            const float* __restrict__ bk,
                                            const float* __restrict__ q2,
                                            float* __restrict__ wk,
                                            float* __restrict__ kb) {
  if (blockIdx.x == 16) {
    int h = threadIdx.x;
    if (h < 8) {
      float acc = 0.f;
      for (int dd = 0; dd < 64; ++dd) acc += q2[h * 64 + dd] * bk[h * 64 + dd];
      kb[h] = acc;
    }
    return;
  }
  int id = blockIdx.x * 256 + threadIdx.x;
  int h = id >> 9, e = id & 511;
  float acc = 0.f;
  #pragma unroll 4
  for (int dd = 0; dd < 64; ++dd)
    acc += q2[h * 64 + dd] * Wk[(size_t)(h * 64 + dd) * 512 + e];
  wk[id] = acc;
}

// ---------------- K2: head-half waves, zero-LDS, barrier-free ----------------
// Block = 4 waves = 2 graphs x 2 head-half waves. Each wave streams ALL nodes
// of its graph (2 per iter, double-buffered), owns heads [4hh,4hh+4) fully:
// complete S and denominators in-wave, epilogue via readlane. LDS = 0, no
// __syncthreads anywhere -> occupancy VGPR-bound (~4 waves/SIMD), shfl chain
// hidden by TLP. Butterfly + slot mapping proven in r11 (absmax 4.9e-4):
// slot at lane l&7: head = 2*bit2 + bit1, node-parity = bit0.

#define PREF(T, X0, X1, X2, X3)                      \
  {                                                  \
    int i0_ = s + 2 * (T);                           \
    int ia_ = i0_ < em1 ? i0_ : em1;                 \
    int ib_ = i0_ + 1 < em1 ? i0_ + 1 : em1;         \
    size_t oa_ = (size_t)ia_ * 128 + lane;           \
    X0 = emb4[oa_]; X1 = emb4[oa_ + 64];             \
    size_t ob_ = (size_t)ib_ * 128 + lane;           \
    X2 = emb4[ob_]; X3 = emb4[ob_ + 64];             \
  }

#define PROC(T, X0, X1, X2, X3)                                                 \
  {                                                                             \
    float pp[8];                                                                \
    _Pragma("unroll")                                                           \
    for (int h = 0; h < 4; ++h) {                                               \
      f32x2 pa = pk_mul(X0.xy, wkA[h].xy);                                      \
      pk_fma_acc(pa, X0.zw, wkA[h].zw);                                         \
      pk_fma_acc(pa, X1.xy, wkB[h].xy);                                         \
      pk_fma_acc(pa, X1.zw, wkB[h].zw);                                         \
      f32x2 pb = pk_mul(X2.xy, wkA[h].xy);                                      \
      pk_fma_acc(pb, X2.zw, wkA[h].zw);                                         \
      pk_fma_acc(pb, X3.xy, wkB[h].xy);                                         \
      pk_fma_acc(pb, X3.zw, wkB[h].zw);                                         \
      pp[2 * h] = pa.x + pa.y;                                                  \
      pp[2 * h + 1] = pb.x + pb.y;                                              \
    }                                                                           \
    float q[4];                                                                 \
    _Pragma("unroll")                                                           \
    for (int h = 0; h < 4; ++h) {                                               \
      float keep = (lane & 1) ? pp[2 * h + 1] : pp[2 * h];                      \
      float send = (lane & 1) ? pp[2 * h] : pp[2 * h + 1];                      \
      q[h] = keep + __shfl_xor(send, 1);                                        \
    }                                                                           \
    float r[2];                                                                 \
    _Pragma("unroll")                                                           \
    for (int j = 0; j < 2; ++j) {                                               \
      float keep = (lane & 2) ? q[2 * j + 1] : q[2 * j];                        \
      float send = (lane & 2) ? q[2 * j] : q[2 * j + 1];                        \
      r[j] = keep + __shfl_xor(send, 2);                                        \
    }                                                                           \
    float sv;                                                                   \
    {                                                                           \
      float keep = (lane & 4) ? r[1] : r[0];                                    \
      float send = (lane & 4) ? r[0] : r[1];                                    \
      sv = keep + __shfl_xor(send, 4);                                          \
    }                                                                           \
    sv += __shfl_xor(sv, 8);                                                    \
    sv += __shfl_xor(sv, 16);                                                   \
    sv += __shfl_xor(sv, 32);                                                   \
    int idxl = s + 2 * (T) + (lane & 1);                                        \
    float ex = exp2f(sv + kbsel);                                               \
    float wgt = (idxl < e2) ? ex : 0.f;                                         \
    dn += wgt;                                                                  \
    float a0 = readlane_f(wgt, 0), b0 = readlane_f(wgt, 1);                     \
    float a1 = readlane_f(wgt, 2), b1 = readlane_f(wgt, 3);                     \
    float a2 = readlane_f(wgt, 4), b2 = readlane_f(wgt, 5);                     \
    float a3 = readlane_f(wgt, 6), b3 = readlane_f(wgt, 7);                     \
    f32x2 va0 = {a0, a0}, vb0 = {b0, b0};                                       \
    f32x2 va1 = {a1, a1}, vb1 = {b1, b1};                                       \
    f32x2 va2 = {a2, a2}, vb2 = {b2, b2};                                       \
    f32x2 va3 = {a3, a3}, vb3 = {b3, b3};                                       \
    pk_fma_acc(SAlo[0], X0.xy, va0); pk_fma_acc(SAlo[0], X2.xy, vb0);           \
    pk_fma_acc(SAhi[0], X0.zw, va0); pk_fma_acc(SAhi[0], X2.zw, vb0);           \
    pk_fma_acc(SBlo[0], X1.xy, va0); pk_fma_acc(SBlo[0], X3.xy, vb0);           \
    pk_fma_acc(SBhi[0], X1.zw, va0); pk_fma_acc(SBhi[0], X3.zw, vb0);           \
    pk_fma_acc(SAlo[1], X0.xy, va1); pk_fma_acc(SAlo[1], X2.xy, vb1);           \
    pk_fma_acc(SAhi[1], X0.zw, va1); pk_fma_acc(SAhi[1], X2.zw, vb1);           \
    pk_fma_acc(SBlo[1], X1.xy, va1); pk_fma_acc(SBlo[1], X3.xy, vb1);           \
    pk_fma_acc(SBhi[1], X1.zw, va1); pk_fma_acc(SBhi[1], X3.zw, vb1);           \
    pk_fma_acc(SAlo[2], X0.xy, va2); pk_fma_acc(SAlo[2], X2.xy, vb2);           \
    pk_fma_acc(SAhi[2], X0.zw, va2); pk_fma_acc(SAhi[2], X2.zw, vb2);           \
    pk_fma_acc(SBlo[2], X1.xy, va2); pk_fma_acc(SBlo[2], X3.xy, vb2);           \
    pk_fma_acc(SBhi[2], X1.zw, va2); pk_fma_acc(SBhi[2], X3.zw, vb2);           \
    pk_fma_acc(SAlo[3], X0.xy, va3); pk_fma_acc(SAlo[3], X2.xy, vb3);           \
    pk_fma_acc(SAhi[3], X0.zw, va3); pk_fma_acc(SAhi[3], X2.zw, vb3);           \
    pk_fma_acc(SBlo[3], X1.xy, va3); pk_fma_acc(SBlo[3], X3.xy, vb3);           \
    pk_fma_acc(SBhi[3], X1.zw, va3); pk_fma_acc(SBhi[3], X3.zw, vb3);           \
  }

__global__ __launch_bounds__(256, 2) void k_main(const float* __restrict__ emb,
                                                 const int* __restrict__ seg,
                                                 const float* __restrict__ wk,
                                                 const float* __restrict__ kb,
                                                 unsigned short* __restrict__ S_out) {
  const int tid = threadIdx.x;
  const int lane = tid & 63, wave = tid >> 6;
  const int g = blockIdx.x * 2 + (wave >> 1);
  const int hh = wave & 1;
  const int s = seg[g], e2 = seg[g + 1];
  const int nt = e2 - s, em1 = e2 - 1;
  const int it = (nt + 1) >> 1;

  f32x4 wkA[4], wkB[4];
  #pragma unroll
  for (int h = 0; h < 4; ++h) {
    wkA[h] = *(const f32x4*)(wk + (hh * 4 + h) * 512 + 4 * lane);
    wkB[h] = *(const f32x4*)(wk + (hh * 4 + h) * 512 + 256 + 4 * lane);
  }
  // slot at lane: head = 2*bit2 + bit1, node-parity = bit0
  const float kbsel = kb[hh * 4 + 2 * ((lane >> 2) & 1) + ((lane >> 1) & 1)];
  const f32x4* emb4 = (const f32x4*)emb;
  const f32x2 Z2 = {0.f, 0.f};

  f32x2 SAlo[4], SAhi[4], SBlo[4], SBhi[4];
  #pragma unroll
  for (int h = 0; h < 4; ++h) {
    SAlo[h] = Z2; SAhi[h] = Z2; SBlo[h] = Z2; SBhi[h] = Z2;
  }
  float dn = 0.f;

  if (it > 0) {
    f32x4 A0, A1, A2, A3, B0, B1, B2, B3;
    PREF(0, A0, A1, A2, A3);
    int t = 0;
    while (true) {
      PREF(t + 1, B0, B1, B2, B3);
      PROC(t, A0, A1, A2, A3);
      ++t; if (t >= it) break;
      PREF(t + 1, A0, A1, A2, A3);
      PROC(t, B0, B1, B2, B3);
      ++t; if (t >= it) break;
    }
  }

  // ---- in-wave epilogue: denom via readlane (dn replicated per 8-lane slot) ----
  #pragma unroll
  for (int h = 0; h < 4; ++h) {
    float d = readlane_f(dn, 2 * h) + readlane_f(dn, 2 * h + 1);
    float invd = d > 0.f ? 1.f / d : 0.f;
    unsigned short* po = S_out + ((size_t)(hh * 4 + h) * 4096 + g) * 512;
    uint2 v;
    v.x = pack2(SAlo[h].x * invd, SAlo[h].y * invd);
    v.y = pack2(SAhi[h].x * invd, SAhi[h].y * invd);
    *(uint2*)(po + 4 * lane) = v;
    v.x = pack2(SBlo[h].x * invd, SBlo[h].y * invd);
    v.y = pack2(SBhi[h].x * invd, SBhi[h].y * invd);
    *(uint2*)(po + 256 + 4 * lane) = v;
  }
}

// ---------------- K3/K4: MFMA NT GEMM ----------------
template <bool C_BF16>
__global__ __launch_bounds__(256) void k_gemm_mfma(
    const unsigned short* __restrict__ A, size_t a_cb_stride,
    const unsigned short* __restrict__ Whi, const unsigned short* __restrict__ Wlo,
    const float* __restrict__ bias, void* __restrict__ Cv) {
  const int t = threadIdx.x;
  const int lane = t & 63, wvid = t >> 6;
  const int wr = wvid >> 1, wc = wvid & 1;
  const int row16 = lane & 15;
  const int k8 = (lane >> 4) * 8;
  const int mbase = blockIdx.x * 64 + wr * 32;
  const int nbase = blockIdx.y * 64 + wc * 32;

  const unsigned short* Ap = A + (size_t)blockIdx.y * a_cb_stride +
                             (size_t)(mbase + row16) * 512 + k8;
  const unsigned short* Wh = Whi + (size_t)(nbase + row16) * 512 + k8;
  const unsigned short* Wl = Wlo + (size_t)(nbase + row16) * 512 + k8;

  f32x4 acc[2][2] = {};

  #pragma unroll 4
  for (int kk = 0; kk < 512; kk += 32) {
    bf16x8 a0 = *(const bf16x8*)(Ap + kk);
    bf16x8 a1 = *(const bf16x8*)(Ap + 16 * 512 + kk);
    bf16x8 h0 = *(const bf16x8*)(Wh + kk);
    bf16x8 h1 = *(const bf16x8*)(Wh + 16 * 512 + kk);
    bf16x8 l0 = *(const bf16x8*)(Wl + kk);
    bf16x8 l1 = *(const bf16x8*)(Wl + 16 * 512 + kk);
    acc[0][0] = __builtin_amdgcn_mfma_f32_16x16x32_bf16(a0, h0, acc[0][0], 0, 0, 0);
    acc[0][1] = __builtin_amdgcn_mfma_f32_16x16x32_bf16(a0, h1, acc[0][1], 0, 0, 0);
    acc[1][0] = __builtin_amdgcn_mfma_f32_16x16x32_bf16(a1, h0, acc[1][0], 0, 0, 0);
    acc[1][1] = __builtin_amdgcn_mfma_f32_16x16x32_bf16(a1, h1, acc[1][1], 0, 0, 0);
    acc[0][0] = __builtin_amdgcn_mfma_f32_16x16x32_bf16(a0, l0, acc[0][0], 0, 0, 0);
    acc[0][1] = __builtin_amdgcn_mfma_f32_16x16x32_bf16(a0, l1, acc[0][1], 0, 0, 0);
    acc[1][0] = __builtin_amdgcn_mfma_f32_16x16x32_bf16(a1, l0, acc[1][0], 0, 0, 0);
    acc[1][1] = __builtin_amdgcn_mfma_f32_16x16x32_bf16(a1, l1, acc[1][1], 0, 0, 0);
  }

  const int r4 = (lane >> 4) * 4;
  #pragma unroll
  for (int c = 0; c < 2; ++c) {
    const float bc = bias[nbase + c * 16 + row16];
    #pragma unroll
    for (int r = 0; r < 2; ++r) {
      #pragma unroll
      for (int j = 0; j < 4; ++j) {
        float v = acc[r][c][j] + bc;
        size_t row = (size_t)(mbase + r * 16 + r4 + j);
        size_t col = (size_t)(nbase + c * 16 + row16);
        if (C_BF16)
          ((unsigned short*)Cv)[row * 512 + col] = f2bf(v);
        else
          ((float*)Cv)[row * 512 + col] = v;
      }
    }
  }
}

// ---------------- launcher ----------------
extern "C" void kernel_launch(void* const* d_in, const int* in_sizes, int n_in,
                              void* d_out, int out_size, void* d_ws, size_t ws_size,
                              hipStream_t stream) {
  const float* emb   = (const float*)d_in[0];
  const void*  batch = d_in[1];
  const float* qry   = (const float*)d_in[2];
  const float* Wq    = (const float*)d_in[3];
  const float* bq    = (const float*)d_in[4];
  const float* Wk    = (const float*)d_in[5];
  const float* bk    = (const float*)d_in[6];
  const float* Wv    = (const float*)d_in[7];
  const float* bv    = (const float*)d_in[8];
  const float* Wo    = (const float*)d_in[9];
  const float* bo    = (const float*)d_in[10];
  const int N = in_sizes[1];

  if (ws_size < WS_NEEDED) return;

  char* ws = (char*)d_ws;
  float* wk_eff = (float*)(ws + WK_OFF);
  float* kbias  = (float*)(ws + KB_OFF);
  float* q2     = (float*)(ws + Q2_OFF);
  int*   seg    = (int*)(ws + SEG_OFF);
  unsigned short* S_ws = (unsigned short*)(ws + S_OFF);
  unsigned short* attn = (unsigned short*)(ws + ATTN_OFF);
  unsigned short* wvhi = (unsigned short*)(ws + WVHI_OFF);
  unsigned short* wvlo = (unsigned short*)(ws + WVLO_OFF);
  unsigned short* wohi = (unsigned short*)(ws + WOHI_OFF);
  unsigned short* wolo = (unsigned short*)(ws + WOLO_OFF);

  k_prep<<<1043, 256, 0, stream>>>(Wv, Wo, wvhi, wvlo, wohi, wolo,
                                   batch, N, seg, qry, Wq, bq, q2);
  k_wk  <<<17, 256, 0, stream>>>(Wk, bk, q2, wk_eff, kbias);
  k_main<<<2048, 256, 0, stream>>>(emb, seg, wk_eff, kbias, S_ws);
  dim3 g(64, 8);
  k_gemm_mfma<true ><<<g, 256, 0, stream>>>(S_ws, (size_t)4096 * 512, wvhi, wvlo, bv, attn);
  k_gemm_mfma<false><<<g, 256, 0, stream>>>(attn, 0, wohi, wolo, bo, d_out);
}

// Round 13
// 341.635 us; speedup vs baseline: 26.6826x; 1.0422x over previous
//
#include <hip/hip_runtime.h>

#define LOG2E 1.4426950408889634f

// ---------------- ws layout (bytes) ----------------
#define WK_OFF   ((size_t)0)          // wk_eff f32 [8][512]
#define KB_OFF   ((size_t)16384)      // kbias f32 [8]
#define Q2_OFF   ((size_t)16416)      // q2 f32 [512]
#define SEG_OFF  ((size_t)18464)      // seg i32 [4097]
#define S_OFF    ((size_t)34880)      // S_ws bf16 [8][4096][512]
#define ATTN_OFF ((size_t)33589312)   // attn bf16 [4096][512]
#define WVHI_OFF ((size_t)37783616)   // Wv hi bf16 [512*512]
#define WVLO_OFF ((size_t)38307904)
#define WOHI_OFF ((size_t)38832192)
#define WOLO_OFF ((size_t)39356480)
#define WS_NEEDED ((size_t)39880768)

typedef __bf16 bf16x8 __attribute__((ext_vector_type(8)));
typedef float f32x4 __attribute__((ext_vector_type(4)));
typedef float f32x2 __attribute__((ext_vector_type(2)));

__device__ __forceinline__ float readlane_f(float v, int l) {
  return __int_as_float(__builtin_amdgcn_readlane(__float_as_int(v), l));
}

__device__ __forceinline__ unsigned short f2bf(float x) {
  unsigned u = __float_as_uint(x);
  unsigned r = (u + 0x7fffu + ((u >> 16) & 1u)) >> 16;
  return (unsigned short)r;
}

__device__ __forceinline__ unsigned pack2(float x, float y) {
  return (unsigned)f2bf(x) | ((unsigned)f2bf(y) << 16);
}

__device__ __forceinline__ float bf2f(unsigned short h) {
  return __uint_as_float((unsigned)h << 16);
}

// packed f32 math (VOP3P): 2 FLOP per issue slot
__device__ __forceinline__ void pk_fma_acc(f32x2& acc, f32x2 a, f32x2 b) {
  asm("v_pk_fma_f32 %0, %1, %2, %0" : "+v"(acc) : "v"(a), "v"(b));
}
__device__ __forceinline__ f32x2 pk_mul(f32x2 a, f32x2 b) {
  f32x2 d;
  asm("v_pk_mul_f32 %0, %1, %2" : "=v"(d) : "v"(a), "v"(b));
  return d;
}

// ---------------- K0: fused prep (W hi/lo split + seg lower_bound + q2) ----------------
__global__ __launch_bounds__(256) void k_prep(
    const float* __restrict__ Wv, const float* __restrict__ Wo,
    unsigned short* __restrict__ wvhi, unsigned short* __restrict__ wvlo,
    unsigned short* __restrict__ wohi, unsigned short* __restrict__ wolo,
    const void* __restrict__ batch, int n, int* __restrict__ seg,
    const float* __restrict__ qry, const float* __restrict__ Wq,
    const float* __restrict__ bq, float* __restrict__ q2) {
  int bx = blockIdx.x;
  if (bx < 1024) {
    int i = bx * 256 + threadIdx.x;
    float v = Wv[i];
    unsigned short h = f2bf(v);
    wvhi[i] = h;
    wvlo[i] = f2bf(v - bf2f(h));
    float o = Wo[i];
    unsigned short h2 = f2bf(o);
    wohi[i] = h2;
    wolo[i] = f2bf(o - bf2f(h2));
  } else if (bx < 1041) {
    int b = (bx - 1024) * 256 + threadIdx.x;
    if (b > 4096) return;
    const int* b32 = (const int*)batch;
    const long long* b64 = (const long long*)batch;
    bool is64 = (b32[n - 1] == 0);
    int lo = 0, hi = n;
    while (lo < hi) {
      int mid = (lo + hi) >> 1;
      long long v = is64 ? b64[mid] : (long long)b32[mid];
      if (v < (long long)b) lo = mid + 1; else hi = mid;
    }
    seg[b] = lo;
  } else {
    int d = (bx - 1041) * 256 + threadIdx.x;
    const float4* q4 = (const float4*)qry;
    const float4* w4 = (const float4*)(Wq + (size_t)d * 512);
    float acc = 0.f;
    #pragma unroll 4
    for (int j = 0; j < 128; ++j) {
      float4 a = q4[j], b = w4[j];
      acc += a.x * b.x + a.y * b.y + a.z * b.z + a.w * b.w;
    }
    q2[d] = (acc + bq[d]) * (0.125f * LOG2E);
  }
}

// ---------------- K1: wk_eff + kbias ----------------
__global__ __launch_bounds__(256) void k_wk(const float* __restrict__ Wk,
                                            const float* __restrict__ bk,
                                            const float* __restrict__ q2,
                                            float* __restrict__ wk,
                                            float* __restrict__ kb) {
  if (blockIdx.x == 16) {
    int h = threadIdx.x;
    if (h < 8) {
      float acc = 0.f;
      for (int dd = 0; dd < 64; ++dd) acc += q2[h * 64 + dd] * bk[h * 64 + dd];
      kb[h] = acc;
    }
    return;
  }
  int id = blockIdx.x * 256 + threadIdx.x;
  int h = id >> 9, e = id & 511;
  float acc = 0.f;
  #pragma unroll 4
  for (int dd = 0; dd < 64; ++dd)
    acc += q2[h * 64 + dd] * Wk[(size_t)(h * 64 + dd) * 512 + e];
  wk[id] = acc;
}

// ---------------- K2: (head-half x node-parity), r11-proven loop, 16KB epilogue ----------------
// 4 waves: wave = (hh, np). Wave owns heads [4hh,4hh+4), nodes s+4t+np,
// s+4t+np+2. Loop is barrier/LDS-free (r11, measured 229 us). Epilogue now
// combines in TWO 256-dim passes so LDS = 16.5 KB -> 8 blocks/CU (was 33 KB
// -> 4 blocks/CU, 31% occupancy): doubles waves-in-flight to hide the
// shfl/exp2 chain. Slot at lane l&7: head = 2*bit2 + bit1, n = bit0.

#define PREF(T, X0, X1, X2, X3)                      \
  {                                                  \
    int i0_ = s + 4 * (T) + np;                      \
    int ia_ = i0_ < em1 ? i0_ : em1;                 \
    int ib_ = i0_ + 2 < em1 ? i0_ + 2 : em1;         \
    size_t oa_ = (size_t)ia_ * 128 + lane;           \
    X0 = emb4[oa_]; X1 = emb4[oa_ + 64];             \
    size_t ob_ = (size_t)ib_ * 128 + lane;           \
    X2 = emb4[ob_]; X3 = emb4[ob_ + 64];             \
  }

#define PROC(T, X0, X1, X2, X3)                                                 \
  {                                                                             \
    float pp[8];                                                                \
    _Pragma("unroll")                                                           \
    for (int h = 0; h < 4; ++h) {                                               \
      f32x2 pa = pk_mul(X0.xy, wkA[h].xy);                                      \
      pk_fma_acc(pa, X0.zw, wkA[h].zw);                                         \
      pk_fma_acc(pa, X1.xy, wkB[h].xy);                                         \
      pk_fma_acc(pa, X1.zw, wkB[h].zw);                                         \
      f32x2 pb = pk_mul(X2.xy, wkA[h].xy);                                      \
      pk_fma_acc(pb, X2.zw, wkA[h].zw);                                         \
      pk_fma_acc(pb, X3.xy, wkB[h].xy);                                         \
      pk_fma_acc(pb, X3.zw, wkB[h].zw);                                         \
      pp[2 * h] = pa.x + pa.y;                                                  \
      pp[2 * h + 1] = pb.x + pb.y;                                              \
    }                                                                           \
    float q[4];                                                                 \
    _Pragma("unroll")                                                           \
    for (int h = 0; h < 4; ++h) {                                               \
      float keep = (lane & 1) ? pp[2 * h + 1] : pp[2 * h];                      \
      float send = (lane & 1) ? pp[2 * h] : pp[2 * h + 1];                      \
      q[h] = keep + __shfl_xor(send, 1);                                        \
    }                                                                           \
    float r[2];                                                                 \
    _Pragma("unroll")                                                           \
    for (int j = 0; j < 2; ++j) {                                               \
      float keep = (lane & 2) ? q[2 * j + 1] : q[2 * j];                        \
      float send = (lane & 2) ? q[2 * j] : q[2 * j + 1];                        \
      r[j] = keep + __shfl_xor(send, 2);                                        \
    }                                                                           \
    float sv;                                                                   \
    {                                                                           \
      float keep = (lane & 4) ? r[1] : r[0];                                    \
      float send = (lane & 4) ? r[0] : r[1];                                    \
      sv = keep + __shfl_xor(send, 4);                                          \
    }                                                                           \
    sv += __shfl_xor(sv, 8);                                                    \
    sv += __shfl_xor(sv, 16);                                                   \
    sv += __shfl_xor(sv, 32);                                                   \
    int idxl = s + 4 * (T) + np + 2 * (lane & 1);                               \
    float ex = exp2f(sv + kbsel);                                               \
    float wgt = (idxl < e2) ? ex : 0.f;                                         \
    dn += wgt;                                                                  \
    float a0 = readlane_f(wgt, 0), b0 = readlane_f(wgt, 1);                     \
    float a1 = readlane_f(wgt, 2), b1 = readlane_f(wgt, 3);                     \
    float a2 = readlane_f(wgt, 4), b2 = readlane_f(wgt, 5);                     \
    float a3 = readlane_f(wgt, 6), b3 = readlane_f(wgt, 7);                     \
    f32x2 va0 = {a0, a0}, vb0 = {b0, b0};                                       \
    f32x2 va1 = {a1, a1}, vb1 = {b1, b1};                                       \
    f32x2 va2 = {a2, a2}, vb2 = {b2, b2};                                       \
    f32x2 va3 = {a3, a3}, vb3 = {b3, b3};                                       \
    pk_fma_acc(SAlo[0], X0.xy, va0); pk_fma_acc(SAlo[0], X2.xy, vb0);           \
    pk_fma_acc(SAhi[0], X0.zw, va0); pk_fma_acc(SAhi[0], X2.zw, vb0);           \
    pk_fma_acc(SBlo[0], X1.xy, va0); pk_fma_acc(SBlo[0], X3.xy, vb0);           \
    pk_fma_acc(SBhi[0], X1.zw, va0); pk_fma_acc(SBhi[0], X3.zw, vb0);           \
    pk_fma_acc(SAlo[1], X0.xy, va1); pk_fma_acc(SAlo[1], X2.xy, vb1);           \
    pk_fma_acc(SAhi[1], X0.zw, va1); pk_fma_acc(SAhi[1], X2.zw, vb1);           \
    pk_fma_acc(SBlo[1], X1.xy, va1); pk_fma_acc(SBlo[1], X3.xy, vb1);           \
    pk_fma_acc(SBhi[1], X1.zw, va1); pk_fma_acc(SBhi[1], X3.zw, vb1);           \
    pk_fma_acc(SAlo[2], X0.xy, va2); pk_fma_acc(SAlo[2], X2.xy, vb2);           \
    pk_fma_acc(SAhi[2], X0.zw, va2); pk_fma_acc(SAhi[2], X2.zw, vb2);           \
    pk_fma_acc(SBlo[2], X1.xy, va2); pk_fma_acc(SBlo[2], X3.xy, vb2);           \
    pk_fma_acc(SBhi[2], X1.zw, va2); pk_fma_acc(SBhi[2], X3.zw, vb2);           \
    pk_fma_acc(SAlo[3], X0.xy, va3); pk_fma_acc(SAlo[3], X2.xy, vb3);           \
    pk_fma_acc(SAhi[3], X0.zw, va3); pk_fma_acc(SAhi[3], X2.zw, vb3);           \
    pk_fma_acc(SBlo[3], X1.xy, va3); pk_fma_acc(SBlo[3], X3.xy, vb3);           \
    pk_fma_acc(SBhi[3], X1.zw, va3); pk_fma_acc(SBhi[3], X3.zw, vb3);           \
  }

__global__ __launch_bounds__(256, 2) void k_main(const float* __restrict__ emb,
                                                 const int* __restrict__ seg,
                                                 const float* __restrict__ wk,
                                                 const float* __restrict__ kb,
                                                 unsigned short* __restrict__ S_out) {
  __shared__ float ep[4][1024];   // 16 KB epilogue combine (two passes)
  __shared__ float dnl[4][8];     // [wave][slot]

  const int tid = threadIdx.x;
  const int lane = tid & 63, wave = tid >> 6;
  const int hh = wave >> 1, np = wave & 1;
  const int b = blockIdx.x;
  const int s = seg[b], e2 = seg[b + 1];
  const int nt = e2 - s, em1 = e2 - 1;
  const int it = (nt + 3) >> 2;

  f32x4 wkA[4], wkB[4];
  #pragma unroll
  for (int h = 0; h < 4; ++h) {
    wkA[h] = *(const f32x4*)(wk + (hh * 4 + h) * 512 + 4 * lane);
    wkB[h] = *(const f32x4*)(wk + (hh * 4 + h) * 512 + 256 + 4 * lane);
  }
  // slot at lane: head = 2*bit2 + bit1, node-parity = bit0
  const float kbsel = kb[hh * 4 + 2 * ((lane >> 2) & 1) + ((lane >> 1) & 1)];
  const f32x4* emb4 = (const f32x4*)emb;
  const f32x2 Z2 = {0.f, 0.f};

  f32x2 SAlo[4], SAhi[4], SBlo[4], SBhi[4];
  #pragma unroll
  for (int h = 0; h < 4; ++h) {
    SAlo[h] = Z2; SAhi[h] = Z2; SBlo[h] = Z2; SBhi[h] = Z2;
  }
  float dn = 0.f;

  if (it > 0) {
    f32x4 A0, A1, A2, A3, B0, B1, B2, B3;
    PREF(0, A0, A1, A2, A3);
    int t = 0;
    while (true) {
      PREF(t + 1, B0, B1, B2, B3);
      PROC(t, A0, A1, A2, A3);
      ++t; if (t >= it) break;
      PREF(t + 1, A0, A1, A2, A3);
      PROC(t, B0, B1, B2, B3);
      ++t; if (t >= it) break;
    }
  }

  // ---- epilogue pass A: dims [0,256) ----
  #pragma unroll
  for (int h = 0; h < 4; ++h) {
    f32x4 tA;
    tA.xy = SAlo[h]; tA.zw = SAhi[h];
    *(f32x4*)&ep[wave][h * 256 + 4 * lane] = tA;
  }
  if (lane < 8) dnl[wave][lane] = dn;
  __syncthreads();
  {
    const int head = tid >> 5, j = tid & 31;
    const int hh2 = head >> 2, hl = head & 3;
    const int l0 = 2 * (hl & 1) + 4 * (hl >> 1);
    const int d0 = j * 8;
    float d = dnl[2 * hh2][l0] + dnl[2 * hh2][l0 + 1] +
              dnl[2 * hh2 + 1][l0] + dnl[2 * hh2 + 1][l0 + 1];
    float invd = d > 0.f ? 1.f / d : 0.f;
    const float* pa = &ep[2 * hh2][hl * 256 + d0];
    const float* pb = &ep[2 * hh2 + 1][hl * 256 + d0];
    unsigned short* po = S_out + ((size_t)head * 4096 + b) * 512 + d0;
    float v[8];
    #pragma unroll
    for (int k = 0; k < 8; ++k) v[k] = (pa[k] + pb[k]) * invd;
    uint4 o;
    o.x = pack2(v[0], v[1]); o.y = pack2(v[2], v[3]);
    o.z = pack2(v[4], v[5]); o.w = pack2(v[6], v[7]);
    *(uint4*)po = o;
  }
  __syncthreads();

  // ---- epilogue pass B: dims [256,512) ----
  #pragma unroll
  for (int h = 0; h < 4; ++h) {
    f32x4 tB;
    tB.xy = SBlo[h]; tB.zw = SBhi[h];
    *(f32x4*)&ep[wave][h * 256 + 4 * lane] = tB;
  }
  __syncthreads();
  {
    const int head = tid >> 5, j = tid & 31;
    const int hh2 = head >> 2, hl = head & 3;
    const int l0 = 2 * (hl & 1) + 4 * (hl >> 1);
    const int d0 = j * 8;
    float d = dnl[2 * hh2][l0] + dnl[2 * hh2][l0 + 1] +
              dnl[2 * hh2 + 1][l0] + dnl[2 * hh2 + 1][l0 + 1];
    float invd = d > 0.f ? 1.f / d : 0.f;
    const float* pa = &ep[2 * hh2][hl * 256 + d0];
    const float* pb = &ep[2 * hh2 + 1][hl * 256 + d0];
    unsigned short* po = S_out + ((size_t)head * 4096 + b) * 512 + 256 + d0;
    float v[8];
    #pragma unroll
    for (int k = 0; k < 8; ++k) v[k] = (pa[k] + pb[k]) * invd;
    uint4 o;
    o.x = pack2(v[0], v[1]); o.y = pack2(v[2], v[3]);
    o.z = pack2(v[4], v[5]); o.w = pack2(v[6], v[7]);
    *(uint4*)po = o;
  }
}

// ---------------- K3/K4: MFMA NT GEMM ----------------
template <bool C_BF16>
__global__ __launch_bounds__(256) void k_gemm_mfma(
    const unsigned short* __restrict__ A, size_t a_cb_stride,
    const unsigned short* __restrict__ Whi, const unsigned short* __restrict__ Wlo,
    const float* __restrict__ bias, void* __restrict__ Cv) {
  const int t = threadIdx.x;
  const int lane = t & 63, wvid = t >> 6;
  const int wr = wvid >> 1, wc = wvid & 1;
  const int row16 = lane & 15;
  const int k8 = (lane >> 4) * 8;
  const int mbase = blockIdx.x * 64 + wr * 32;
  const int nbase = blockIdx.y * 64 + wc * 32;

  const unsigned short* Ap = A + (size_t)blockIdx.y * a_cb_stride +
                             (size_t)(mbase + row16) * 512 + k8;
  const unsigned short* Wh = Whi + (size_t)(nbase + row16) * 512 + k8;
  const unsigned short* Wl = Wlo + (size_t)(nbase + row16) * 512 + k8;

  f32x4 acc[2][2] = {};

  #pragma unroll 4
  for (int kk = 0; kk < 512; kk += 32) {
    bf16x8 a0 = *(const bf16x8*)(Ap + kk);
    bf16x8 a1 = *(const bf16x8*)(Ap + 16 * 512 + kk);
    bf16x8 h0 = *(const bf16x8*)(Wh + kk);
    bf16x8 h1 = *(const bf16x8*)(Wh + 16 * 512 + kk);
    bf16x8 l0 = *(const bf16x8*)(Wl + kk);
    bf16x8 l1 = *(const bf16x8*)(Wl + 16 * 512 + kk);
    acc[0][0] = __builtin_amdgcn_mfma_f32_16x16x32_bf16(a0, h0, acc[0][0], 0, 0, 0);
    acc[0][1] = __builtin_amdgcn_mfma_f32_16x16x32_bf16(a0, h1, acc[0][1], 0, 0, 0);
    acc[1][0] = __builtin_amdgcn_mfma_f32_16x16x32_bf16(a1, h0, acc[1][0], 0, 0, 0);
    acc[1][1] = __builtin_amdgcn_mfma_f32_16x16x32_bf16(a1, h1, acc[1][1], 0, 0, 0);
    acc[0][0] = __builtin_amdgcn_mfma_f32_16x16x32_bf16(a0, l0, acc[0][0], 0, 0, 0);
    acc[0][1] = __builtin_amdgcn_mfma_f32_16x16x32_bf16(a0, l1, acc[0][1], 0, 0, 0);
    acc[1][0] = __builtin_amdgcn_mfma_f32_16x16x32_bf16(a1, l0, acc[1][0], 0, 0, 0);
    acc[1][1] = __builtin_amdgcn_mfma_f32_16x16x32_bf16(a1, l1, acc[1][1], 0, 0, 0);
  }

  const int r4 = (lane >> 4) * 4;
  #pragma unroll
  for (int c = 0; c < 2; ++c) {
    const float bc = bias[nbase + c * 16 + row16];
    #pragma unroll
    for (int r = 0; r < 2; ++r) {
      #pragma unroll
      for (int j = 0; j < 4; ++j) {
        float v = acc[r][c][j] + bc;
        size_t row = (size_t)(mbase + r * 16 + r4 + j);
        size_t col = (size_t)(nbase + c * 16 + row16);
        if (C_BF16)
          ((unsigned short*)Cv)[row * 512 + col] = f2bf(v);
        else
          ((float*)Cv)[row * 512 + col] = v;
      }
    }
  }
}

// ---------------- launcher ----------------
extern "C" void kernel_launch(void* const* d_in, const int* in_sizes, int n_in,
                              void* d_out, int out_size, void* d_ws, size_t ws_size,
                              hipStream_t stream) {
  const float* emb   = (const float*)d_in[0];
  const void*  batch = d_in[1];
  const float* qry   = (const float*)d_in[2];
  const float* Wq    = (const float*)d_in[3];
  const float* bq    = (const float*)d_in[4];
  const float* Wk    = (const float*)d_in[5];
  const float* bk    = (const float*)d_in[6];
  const float* Wv    = (const float*)d_in[7];
  const float* bv    = (const float*)d_in[8];
  const float* Wo    = (const float*)d_in[9];
  const float* bo    = (const float*)d_in[10];
  const int N = in_sizes[1];

  if (ws_size < WS_NEEDED) return;

  char* ws = (char*)d_ws;
  float* wk_eff = (float*)(ws + WK_OFF);
  float* kbias  = (float*)(ws + KB_OFF);
  float* q2     = (float*)(ws + Q2_OFF);
  int*   seg    = (int*)(ws + SEG_OFF);
  unsigned short* S_ws = (unsigned short*)(ws + S_OFF);
  unsigned short* attn = (unsigned short*)(ws + ATTN_OFF);
  unsigned short* wvhi = (unsigned short*)(ws + WVHI_OFF);
  unsigned short* wvlo = (unsigned short*)(ws + WVLO_OFF);
  unsigned short* wohi = (unsigned short*)(ws + WOHI_OFF);
  unsigned short* wolo = (unsigned short*)(ws + WOLO_OFF);

  k_prep<<<1043, 256, 0, stream>>>(Wv, Wo, wvhi, wvlo, wohi, wolo,
                                   batch, N, seg, qry, Wq, bq, q2);
  k_wk  <<<17, 256, 0, stream>>>(Wk, bk, q2, wk_eff, kbias);
  k_main<<<4096, 256, 0, stream>>>(emb, seg, wk_eff, kbias, S_ws);
  dim3 g(64, 8);
  k_gemm_mfma<true ><<<g, 256, 0, stream>>>(S_ws, (size_t)4096 * 512, wvhi, wvlo, bv, attn);
  k_gemm_mfma<false><<<g, 256, 0, stream>>>(attn, 0, wohi, wolo, bo, d_out);
}